// Round 9
// baseline (292.931 us; speedup 1.0000x reference)
//
#include <hip/hip_runtime.h>
#include <hip/hip_bf16.h>

// ZoomTransformerBlock: B=2, N=2048, D=1024, H=16, DH=64, DF=4096
// R9: mlp2 -> 8-phase 256^2 GEMM with split-K=4 (grid (4,16,4), f32 atomicAdd
//     epilogue onto proj's freshly-written out; split 0 adds bias);
//     attn -> f32 dist direct (LOG2E folded into gamma), cast kernel removed.
//     Rest identical to R8.

#define SCALE_ 0.03125f   // D^-0.5 = 1/32
#define EPS_   1e-5f
#define LOG2E_ 1.4426950408889634f
#define SC2_   (SCALE_ * LOG2E_)

typedef unsigned short u16;
typedef __attribute__((ext_vector_type(8))) short short8;
typedef __attribute__((ext_vector_type(4))) float f32x4;
typedef __attribute__((ext_vector_type(4))) unsigned short u16x4;

__device__ inline float b2f(u16 u){ unsigned x = ((unsigned)u) << 16; float f; __builtin_memcpy(&f, &x, 4); return f; }
__device__ inline u16 f2b(float f){ __hip_bfloat16 h = __float2bfloat16(f); u16 u; __builtin_memcpy(&u, &h, 2); return u; }

// async global->LDS, 16B per lane; LDS dest = wave-uniform base + lane*16 (linear)
__device__ inline void glds16(const u16* g, u16* l) {
    __builtin_amdgcn_global_load_lds(
        (const __attribute__((address_space(1))) void*)g,
        (__attribute__((address_space(3))) void*)l, 16, 0, 0);
}

// pack 2 f32 -> 1 dword of 2 bf16 (lo = a, hi = b)
__device__ inline unsigned cvtpk(float a, float b) {
    unsigned r;
    asm("v_cvt_pk_bf16_f32 %0, %1, %2" : "=v"(r) : "v"(a), "v"(b));
    return r;
}

// ---------------- transpose + cast: src [K][N] f32 -> dst [N][K] bf16 ----------------
__global__ __launch_bounds__(256) void transpose_cast(const float* __restrict__ src,
                                                      u16* __restrict__ dst, int K, int N) {
    __shared__ float t[32][33];
    int nb = blockIdx.x * 32, kb = blockIdx.y * 32;
    int tx = threadIdx.x & 31, ty = threadIdx.x >> 5;
    for (int i = 0; i < 4; i++) {
        int r = ty + i * 8;
        t[r][tx] = src[(size_t)(kb + r) * N + nb + tx];
    }
    __syncthreads();
    for (int i = 0; i < 4; i++) {
        int r = ty + i * 8;
        dst[(size_t)(nb + r) * K + kb + tx] = f2b(t[tx][r]);
    }
}

// ---------------- LayerNorm row (D=1024) f32 -> bf16 ----------------
__global__ __launch_bounds__(256) void ln_bf16(const float* __restrict__ x,
                                               const float* __restrict__ w,
                                               const float* __restrict__ b,
                                               u16* __restrict__ out) {
    int row = blockIdx.x, t = threadIdx.x;
    float4 v = ((const float4*)(x + (size_t)row * 1024))[t];
    float s1 = v.x + v.y + v.z + v.w;
    float s2 = v.x * v.x + v.y * v.y + v.z * v.z + v.w * v.w;
    for (int o = 32; o > 0; o >>= 1) { s1 += __shfl_xor(s1, o); s2 += __shfl_xor(s2, o); }
    __shared__ float a1[4], a2[4];
    if ((t & 63) == 0) { a1[t >> 6] = s1; a2[t >> 6] = s2; }
    __syncthreads();
    s1 = a1[0] + a1[1] + a1[2] + a1[3];
    s2 = a2[0] + a2[1] + a2[2] + a2[3];
    float mu = s1 * (1.0f / 1024.0f);
    float var = s2 * (1.0f / 1024.0f) - mu * mu;
    float rs = rsqrtf(var + EPS_);
    float4 wv = ((const float4*)w)[t];
    float4 bv = ((const float4*)b)[t];
    u16x4 o;
    o[0] = f2b((v.x - mu) * rs * wv.x + bv.x);
    o[1] = f2b((v.y - mu) * rs * wv.y + bv.y);
    o[2] = f2b((v.z - mu) * rs * wv.z + bv.z);
    o[3] = f2b((v.w - mu) * rs * wv.w + bv.w);
    ((u16x4*)(out + (size_t)row * 1024))[t] = o;
}

// ======== 8-phase 256x256 MFMA GEMM, BK=32, 4-deep K-tile pipeline ========
// MODE 0: qkv scatter (+bias, q pre-scaled)   MODE 2: outb = gelu(acc+bias), ld 4096
// MODE 3: split-K partial, atomicAdd f32 into outf (+bias iff k0==0), ld 1024
template <int MODE>
__global__ __launch_bounds__(512) void gemm256_8ph(
    const u16* __restrict__ A, const u16* __restrict__ Bt,
    const float* __restrict__ bias, int K, int ksl,
    u16* __restrict__ outb, float* __restrict__ outf,
    u16* __restrict__ qp, u16* __restrict__ kp, u16* __restrict__ vtp) {
    __shared__ u16 LS[4][2][256 * 32];   // 128 KiB
    int tid = threadIdx.x;
    int w = tid >> 6, lane = tid & 63, g = lane >> 4, ln = lane & 15;
    int wr = w >> 2, wc = w & 3;
    int gx = gridDim.x;
    int nwg = gx * gridDim.y;
    int lin = blockIdx.y * gx + blockIdx.x;
    int swz = (lin & 7) * (nwg >> 3) + (lin >> 3);
    int bx = swz % gx, by = swz / gx;
    int br = by * 256, bc = bx * 256;
    int k0 = blockIdx.z * ksl;
    int jx = (((lane & 3) ^ ((lane >> 3) & 3)) << 3);
    const u16* Ast = A + (size_t)(br + w * 32 + (lane >> 2)) * K + k0 + jx;
    const u16* Bst = Bt + (size_t)(bc + w * 32 + (lane >> 2)) * K + k0 + jx;
    size_t r16 = (size_t)16 * K;
    const int ldsW = (w * 32) * 32;
    f32x4 acc[8][4] = {};
    int NT = ksl >> 5;
    int slotr = ((g ^ ((ln >> 1) & 3)) << 3);
    for (int kt = 0; kt < 3; ++kt) {
        glds16(Ast + (size_t)kt * 32, &LS[kt][0][ldsW]);
        glds16(Ast + (size_t)kt * 32 + r16, &LS[kt][0][ldsW + 512]);
        glds16(Bst + (size_t)kt * 32, &LS[kt][1][ldsW]);
        glds16(Bst + (size_t)kt * 32 + r16, &LS[kt][1][ldsW + 512]);
    }
    asm volatile("s_waitcnt vmcnt(8)" ::: "memory");
    __builtin_amdgcn_s_barrier();
    short8 aa[4], bb[4];
    for (int kt = 0; kt < NT; ++kt) {
        const u16* bufA = &LS[kt & 3][0][0];
        const u16* bufB = &LS[kt & 3][1][0];
        int s3 = kt + 3;
        #pragma unroll
        for (int m = 0; m < 4; ++m)
            aa[m] = *(const short8*)&bufA[(wr * 128 + m * 16 + ln) * 32 + slotr];
        #pragma unroll
        for (int n = 0; n < 4; ++n)
            bb[n] = *(const short8*)&bufB[(wc * 64 + n * 16 + ln) * 32 + slotr];
        if (s3 < NT) {
            u16* d = &LS[s3 & 3][0][ldsW];
            glds16(Ast + (size_t)s3 * 32, d);
            glds16(Ast + (size_t)s3 * 32 + r16, d + 512);
        }
        __builtin_amdgcn_s_barrier();
        asm volatile("s_waitcnt lgkmcnt(0)" ::: "memory");
        __builtin_amdgcn_sched_barrier(0);
        __builtin_amdgcn_s_setprio(1);
        #pragma unroll
        for (int m = 0; m < 4; ++m)
            #pragma unroll
            for (int n = 0; n < 4; ++n)
                acc[m][n] = __builtin_amdgcn_mfma_f32_16x16x32_bf16(aa[m], bb[n], acc[m][n], 0, 0, 0);
        __builtin_amdgcn_s_setprio(0);
        __builtin_amdgcn_sched_barrier(0);
        __builtin_amdgcn_s_barrier();
        #pragma unroll
        for (int m = 0; m < 4; ++m)
            aa[m] = *(const short8*)&bufA[(wr * 128 + 64 + m * 16 + ln) * 32 + slotr];
        if (s3 < NT) {
            u16* d = &LS[s3 & 3][1][ldsW];
            glds16(Bst + (size_t)s3 * 32, d);
            glds16(Bst + (size_t)s3 * 32 + r16, d + 512);
        }
        if (kt + 3 < NT)      asm volatile("s_waitcnt vmcnt(8)" ::: "memory");
        else if (kt + 2 < NT) asm volatile("s_waitcnt vmcnt(4)" ::: "memory");
        else if (kt + 1 < NT) asm volatile("s_waitcnt vmcnt(0)" ::: "memory");
        __builtin_amdgcn_s_barrier();
        asm volatile("s_waitcnt lgkmcnt(0)" ::: "memory");
        __builtin_amdgcn_sched_barrier(0);
        __builtin_amdgcn_s_setprio(1);
        #pragma unroll
        for (int m = 0; m < 4; ++m)
            #pragma unroll
            for (int n = 0; n < 4; ++n)
                acc[4 + m][n] = __builtin_amdgcn_mfma_f32_16x16x32_bf16(aa[m], bb[n], acc[4 + m][n], 0, 0, 0);
        __builtin_amdgcn_s_setprio(0);
        __builtin_amdgcn_sched_barrier(0);
        __builtin_amdgcn_s_barrier();
    }
    #pragma unroll
    for (int m = 0; m < 8; ++m) {
        int row0 = br + wr * 128 + m * 16 + g * 4;
        #pragma unroll
        for (int n = 0; n < 4; ++n) {
            int col = bc + wc * 64 + n * 16 + ln;
            if constexpr (MODE == 0) {
                float bv = bias[col];
                int which = col >> 10, cc = col & 1023, hh = cc >> 6, dh = cc & 63;
                int bb2 = row0 >> 11, nn0 = row0 & 2047;
                size_t bh = (size_t)(bb2 * 16 + hh);
                if (which == 0) {
                    for (int r = 0; r < 4; r++)
                        qp[((bh * 2048 + nn0 + r) << 6) + dh] = f2b((acc[m][n][r] + bv) * SC2_);
                } else if (which == 1) {
                    for (int r = 0; r < 4; r++)
                        kp[((bh * 2048 + nn0 + r) << 6) + dh] = f2b(acc[m][n][r] + bv);
                } else {
                    u16x4 o;
                    for (int r = 0; r < 4; r++) o[r] = f2b(acc[m][n][r] + bv);
                    *(u16x4*)&vtp[((bh * 64 + dh) << 11) + nn0] = o;
                }
            } else if constexpr (MODE == 2) {
                float bv = bias[col];
                for (int r = 0; r < 4; r++) {
                    float v = acc[m][n][r] + bv;
                    float gl = 0.5f * v * (1.0f + erff(v * 0.7071067811865476f));
                    outb[(size_t)(row0 + r) * 4096 + col] = f2b(gl);
                }
            } else {   // MODE 3: split-K partial accumulate
                float bv = (k0 == 0) ? bias[col] : 0.0f;
                for (int r = 0; r < 4; r++)
                    atomicAdd(&outf[(size_t)(row0 + r) * 1024 + col], acc[m][n][r] + bv);
            }
        }
    }
}

// ---------------- bf16 GEMM (R3/R4 structure): MODE 1: out=res+acc+b ----
template <int MODE, int BN>
__global__ __launch_bounds__(256) void gemm_bf16(
    const u16* __restrict__ A, const u16* __restrict__ Bt,
    const float* __restrict__ bias, int M, int N, int K,
    const float* __restrict__ res, float* __restrict__ outf) {
    constexpr int NN = BN / 32;
    __shared__ u16 As[128 * 64];
    __shared__ u16 Bs[BN * 64];
    int br = blockIdx.y * 128, bc = blockIdx.x * BN;
    int tid = threadIdx.x;
    int w = tid >> 6, lane = tid & 63, g = lane >> 4, ln = lane & 15;
    int wr = (w >> 1) * 64, wc = (w & 1) * (BN / 2);
    f32x4 acc[4][NN] = {};
    int sgcol = (((lane & 7) ^ (lane >> 3)) << 3);
    int arow = w * 32 + (lane >> 3);
    int brow = w * (BN / 4) + (lane >> 3);
    const u16* Ap = A + (size_t)(br + arow) * K + sgcol;
    const u16* Bp = Bt + (size_t)(bc + brow) * K + sgcol;
    u16* lA = &As[(w * 32) * 64];
    u16* lB = &Bs[(w * (BN / 4)) * 64];
    size_t rstep = (size_t)8 * K;
    for (int kt = 0; kt < K; kt += 64) {
        __syncthreads();
        #pragma unroll
        for (int i = 0; i < 4; i++) glds16(Ap + kt + i * rstep, lA + i * 512);
        #pragma unroll
        for (int i = 0; i < BN / 32; i++) glds16(Bp + kt + i * rstep, lB + i * 512);
        __syncthreads();
        #pragma unroll
        for (int kk = 0; kk < 2; kk++) {
            int so = (((kk << 2) + g) ^ (ln & 7)) << 3;
            short8 af[4], bfr[NN];
            #pragma unroll
            for (int m = 0; m < 4; m++)  af[m]  = *(const short8*)&As[(wr + m * 16 + ln) * 64 + so];
            #pragma unroll
            for (int n = 0; n < NN; n++) bfr[n] = *(const short8*)&Bs[(wc + n * 16 + ln) * 64 + so];
            #pragma unroll
            for (int m = 0; m < 4; m++)
                #pragma unroll
                for (int n = 0; n < NN; n++)
                    acc[m][n] = __builtin_amdgcn_mfma_f32_16x16x32_bf16(af[m], bfr[n], acc[m][n], 0, 0, 0);
        }
    }
    #pragma unroll
    for (int m = 0; m < 4; m++) {
        int row0 = br + wr + m * 16 + g * 4;
        #pragma unroll
        for (int n = 0; n < NN; n++) {
            int col = bc + wc + n * 16 + ln;
            float bv = bias[col];
            for (int r = 0; r < 4; r++) {
                size_t idx = (size_t)(row0 + r) * 1024 + col;
                outf[idx] = res[idx] + acc[m][n][r] + bv;
            }
        }
    }
}

// ---------------- flash attention: 8 waves (QBLK=128), swapped QK^T, dbuf LDS ----------------
// grid (16 q-tiles, 32 bh), 8 waves/wg; q pre-scaled by SCALE*LOG2E; dist raw f32.
__global__ __launch_bounds__(512) void attn_fwd(
    const u16* __restrict__ qg, const u16* __restrict__ kg, const u16* __restrict__ vtg,
    const float* __restrict__ dist, const float* __restrict__ gamma, u16* __restrict__ ao) {
    __shared__ u16 Ks[2][64 * 64];   // 16 KB
    __shared__ u16 Vs[2][64 * 64];   // 16 KB (V^T)
    __shared__ u16 Ps[8][16 * 64];   // 16 KB
    int qt = blockIdx.x, bh = blockIdx.y;
    int b = bh >> 4, h = bh & 15;
    int tid = threadIdx.x, w = tid >> 6, lane = tid & 63, g = lane >> 4, ln = lane & 15;
    float gam = gamma[bh] * LOG2E_;
    int qglob = qt * 128 + w * 16 + ln;
    const u16* qrow = qg + ((size_t)bh * 2048 + qglob) * 64;
    short8 qf0 = *(const short8*)(qrow + g * 8);
    short8 qf1 = *(const short8*)(qrow + 32 + g * 8);
    const float* dbase = dist + (size_t)qglob * 2048 + g * 4;
    float m2 = -3.0e38f, lsum = 0.0f;
    f32x4 acco[4] = {};
    // staging: 512 thr cover 64 rows x 8 x 16B for K and V^T; swizzled LDS write
    int srow = tid >> 3, seg = tid & 7;
    int ss = ((seg ^ (srow & 7)) << 3);
    const u16* kgp = kg + ((size_t)bh * 2048 + srow) * 64 + seg * 8;
    const u16* vgp = vtg + ((size_t)bh * 64 + srow) * 2048 + seg * 8;
    {   // prologue: tile 0
        short8 a0 = *(const short8*)(kgp);
        short8 c0 = *(const short8*)(vgp);
        *(short8*)&Ks[0][srow * 64 + ss] = a0;
        *(short8*)&Vs[0][srow * 64 + ss] = c0;
    }
    f32x4 dcv[4];
    #pragma unroll
    for (int nb = 0; nb < 4; nb++) dcv[nb] = *(const f32x4*)(dbase + nb * 16);
    __syncthreads();
    int cur = 0;
    int so0 = (g ^ (ln & 7)) << 3, so1 = ((4 + g) ^ (ln & 7)) << 3;
    for (int kt = 0; kt < 32; kt++) {
        // async-STAGE split: issue next tile's global loads NOW, consume after PV
        short8 kr0, vr0;
        f32x4 dnx[4];
        if (kt < 31) {
            kr0 = *(const short8*)(kgp + (kt + 1) * 4096);
            vr0 = *(const short8*)(vgp + (kt + 1) * 64);
            #pragma unroll
            for (int nb = 0; nb < 4; nb++)
                dnx[nb] = *(const f32x4*)(dbase + (kt + 1) * 64 + nb * 16);
        }
        // S^T = K Q^T : sa[nb][r] = S[kv=nb*16+g*4+r][q=ln]
        f32x4 sa[4] = {};
        __builtin_amdgcn_s_setprio(1);
        #pragma unroll
        for (int nb = 0; nb < 4; nb++) {
            short8 kf0 = *(const short8*)&Ks[cur][(nb * 16 + ln) * 64 + so0];
            short8 kf1 = *(const short8*)&Ks[cur][(nb * 16 + ln) * 64 + so1];
            sa[nb] = __builtin_amdgcn_mfma_f32_16x16x32_bf16(kf0, qf0, sa[nb], 0, 0, 0);
            sa[nb] = __builtin_amdgcn_mfma_f32_16x16x32_bf16(kf1, qf1, sa[nb], 0, 0, 0);
        }
        __builtin_amdgcn_s_setprio(0);
        // softmax in log2 domain (SCALE*LOG2E folded into q; LOG2E in gam)
        float sv[4][4], pm = -3.0e38f;
        #pragma unroll
        for (int nb = 0; nb < 4; nb++) {
            #pragma unroll
            for (int r = 0; r < 4; r++)
                sv[nb][r] = sa[nb][r] - gam * dcv[nb][r];
            pm = fmaxf(pm, fmaxf(fmaxf(sv[nb][0], sv[nb][1]), fmaxf(sv[nb][2], sv[nb][3])));
        }
        pm = fmaxf(pm, __shfl_xor(pm, 16));
        pm = fmaxf(pm, __shfl_xor(pm, 32));
        if (!__all(pm - m2 <= 8.0f)) {   // defer-max: rescale only on real growth
            float nm = fmaxf(m2, pm);
            float al = __builtin_exp2f(m2 - nm);
            m2 = nm;
            lsum *= al;
            #pragma unroll
            for (int db = 0; db < 4; db++) acco[db] *= al;
        }
        float ps = 0.0f;
        #pragma unroll
        for (int nb = 0; nb < 4; nb++) {
            float e0 = __builtin_exp2f(sv[nb][0] - m2);
            float e1 = __builtin_exp2f(sv[nb][1] - m2);
            float e2 = __builtin_exp2f(sv[nb][2] - m2);
            float e3 = __builtin_exp2f(sv[nb][3] - m2);
            ps += (e0 + e1) + (e2 + e3);
            union { unsigned u[2]; u16x4 v; } pk;
            pk.u[0] = cvtpk(e0, e1);
            pk.u[1] = cvtpk(e2, e3);
            int off = nb * 16 + g * 4;
            *(u16x4*)&Ps[w][ln * 64 + (((off >> 3) ^ (ln & 7)) << 3) + (off & 7)] = pk.v;
        }
        ps += __shfl_xor(ps, 16);
        ps += __shfl_xor(ps, 32);
        lsum += ps;
        // PV^T: out^T[d][q] += V^T[d][kv] P^T[kv][q]
        short8 pf0 = *(const short8*)&Ps[w][ln * 64 + so0];
        short8 pf1 = *(const short8*)&Ps[w][ln * 64 + so1];
        __builtin_amdgcn_s_setprio(1);
        #pragma unroll
        for (int db = 0; db < 4; db++) {
            short8 vf0 = *(const short8*)&Vs[cur][(db * 16 + ln) * 64 + so0];
            short8 vf1 = *(const short8*)&Vs[cur][(db * 16 + ln) * 64 + so1];
            acco[db] = __builtin_amdgcn_mfma_f32_16x16x32_bf16(vf0, pf0, acco[db], 0, 0, 0);
            acco[db] = __builtin_amdgcn_mfma_f32_16x16x32_bf16(vf1, pf1, acco[db], 0, 0, 0);
        }
        __builtin_amdgcn_s_setprio(0);
        if (kt < 31) {   // write-late: regs -> other buffer, ONE barrier/tile
            int nx = cur ^ 1;
            *(short8*)&Ks[nx][srow * 64 + ss] = kr0;
            *(short8*)&Vs[nx][srow * 64 + ss] = vr0;
            #pragma unroll
            for (int nb = 0; nb < 4; nb++) dcv[nb] = dnx[nb];
            __syncthreads();
            cur = nx;
        }
    }
    float inv = 1.0f / lsum;
    u16* aop = ao + (size_t)(b * 2048 + qglob) * 1024 + h * 64 + g * 4;
    #pragma unroll
    for (int db = 0; db < 4; db++) {
        u16x4 o;
        #pragma unroll
        for (int r = 0; r < 4; r++) o[r] = f2b(acco[db][r] * inv);
        *(u16x4*)(aop + db * 16) = o;
    }
}

extern "C" void kernel_launch(void* const* d_in, const int* in_sizes, int n_in,
                              void* d_out, int out_size, void* d_ws, size_t ws_size,
                              hipStream_t stream) {
    const float* x     = (const float*)d_in[0];
    const float* gamma = (const float*)d_in[1];
    const float* dist  = (const float*)d_in[2];
    const float* ln1w  = (const float*)d_in[3];
    const float* ln1b  = (const float*)d_in[4];
    const float* qkvw  = (const float*)d_in[5];
    const float* qkvb  = (const float*)d_in[6];
    const float* projw = (const float*)d_in[7];
    const float* projb = (const float*)d_in[8];
    const float* ln2w  = (const float*)d_in[9];
    const float* ln2b  = (const float*)d_in[10];
    const float* w1    = (const float*)d_in[11];
    const float* b1    = (const float*)d_in[12];
    const float* w2    = (const float*)d_in[13];
    const float* b2    = (const float*)d_in[14];
    float* out = (float*)d_out;
    char* ws = (char*)d_ws;
    u16* wqkvT  = (u16*)(ws + 0);
    u16* wprojT = (u16*)(ws + 6291456);
    u16* w1T    = (u16*)(ws + 8388608);
    u16* w2T    = (u16*)(ws + 16777216);
    u16* hb     = (u16*)(ws + 33554432);
    u16* qb     = (u16*)(ws + 41943040);
    u16* kb     = (u16*)(ws + 50331648);
    u16* vtb    = (u16*)(ws + 58720256);
    u16* aob    = (u16*)(ws + 67108864);
    u16* gb     = hb;    // mlp1 output reuses h..vT region (dead by then)
    u16* h2b    = aob;   // ln2 output reuses ao slot (dead after proj)

    dim3 blk(256);
    transpose_cast<<<dim3(3072 / 32, 1024 / 32), blk, 0, stream>>>(qkvw, wqkvT, 1024, 3072);
    transpose_cast<<<dim3(1024 / 32, 1024 / 32), blk, 0, stream>>>(projw, wprojT, 1024, 1024);
    transpose_cast<<<dim3(4096 / 32, 1024 / 32), blk, 0, stream>>>(w1, w1T, 1024, 4096);
    transpose_cast<<<dim3(1024 / 32, 4096 / 32), blk, 0, stream>>>(w2, w2T, 4096, 1024);
    ln_bf16<<<4096, blk, 0, stream>>>(x, ln1w, ln1b, hb);
    gemm256_8ph<0><<<dim3(12, 16), dim3(512), 0, stream>>>(hb, wqkvT, qkvb, 1024, 1024,
                                                           nullptr, nullptr, qb, kb, vtb);
    attn_fwd<<<dim3(16, 32), dim3(512), 0, stream>>>(qb, kb, vtb, dist, gamma, aob);
    gemm_bf16<1, 64><<<dim3(16, 32), blk, 0, stream>>>(aob, wprojT, projb, 4096, 1024, 1024,
                                                       x, out);
    ln_bf16<<<4096, blk, 0, stream>>>(out, ln2w, ln2b, h2b);
    gemm256_8ph<2><<<dim3(16, 16), dim3(512), 0, stream>>>(h2b, w1T, b1, 1024, 1024,
                                                           gb, nullptr, nullptr, nullptr, nullptr);
    gemm256_8ph<3><<<dim3(4, 16, 4), dim3(512), 0, stream>>>(gb, w2T, b2, 4096, 1024,
                                                             nullptr, out, nullptr, nullptr, nullptr);
}

// Round 10
// 291.887 us; speedup vs baseline: 1.0036x; 1.0036x over previous
//
#include <hip/hip_runtime.h>
#include <hip/hip_bf16.h>

// ZoomTransformerBlock: B=2, N=2048, D=1024, H=16, DH=64, DF=4096
// R10: mlp2 reverted to BN=64 2-barrier GEMM (split-K atomics regressed);
//      attn rebuilt: 32x32x16 MFMA, 8 waves = 4 q-subgroups x 2 kv-halves
//      (in-block kv-split, LDS merge), P in registers (cvt_pk+permlane32),
//      K/V staged via global_load_lds w/ pre-swizzled source, dbuf,
//      launch_bounds(512,4) to cap VGPR<=128 (16 waves/CU).

#define SCALE_ 0.03125f   // D^-0.5 = 1/32
#define EPS_   1e-5f
#define LOG2E_ 1.4426950408889634f
#define SC2_   (SCALE_ * LOG2E_)

typedef unsigned short u16;
typedef __attribute__((ext_vector_type(8))) short short8;
typedef __attribute__((ext_vector_type(4))) float f32x4;
typedef __attribute__((ext_vector_type(16))) float f32x16;
typedef __attribute__((ext_vector_type(4))) unsigned short u16x4;

__device__ inline float b2f(u16 u){ unsigned x = ((unsigned)u) << 16; float f; __builtin_memcpy(&f, &x, 4); return f; }
__device__ inline u16 f2b(float f){ __hip_bfloat16 h = __float2bfloat16(f); u16 u; __builtin_memcpy(&u, &h, 2); return u; }

// async global->LDS, 16B per lane; LDS dest = wave-uniform base + lane*16 (linear)
__device__ inline void glds16(const u16* g, u16* l) {
    __builtin_amdgcn_global_load_lds(
        (const __attribute__((address_space(1))) void*)g,
        (__attribute__((address_space(3))) void*)l, 16, 0, 0);
}

// pack 2 f32 -> 1 dword of 2 bf16 (lo = a, hi = b)
__device__ inline unsigned cvtpk(float a, float b) {
    unsigned r;
    asm("v_cvt_pk_bf16_f32 %0, %1, %2" : "=v"(r) : "v"(a), "v"(b));
    return r;
}
// swap a.lanes[32:63] <-> b.lanes[0:31]
__device__ inline void pl32swap(unsigned &a, unsigned &b) {
    asm("v_permlane32_swap_b32 %0, %1" : "+v"(a), "+v"(b));
}
__device__ inline short8 mk8(unsigned a, unsigned b, unsigned c, unsigned d) {
    union { unsigned u[4]; short8 s; } x;
    x.u[0] = a; x.u[1] = b; x.u[2] = c; x.u[3] = d;
    return x.s;
}

// ---------------- transpose + cast: src [K][N] f32 -> dst [N][K] bf16 ----------------
__global__ __launch_bounds__(256) void transpose_cast(const float* __restrict__ src,
                                                      u16* __restrict__ dst, int K, int N) {
    __shared__ float t[32][33];
    int nb = blockIdx.x * 32, kb = blockIdx.y * 32;
    int tx = threadIdx.x & 31, ty = threadIdx.x >> 5;
    for (int i = 0; i < 4; i++) {
        int r = ty + i * 8;
        t[r][tx] = src[(size_t)(kb + r) * N + nb + tx];
    }
    __syncthreads();
    for (int i = 0; i < 4; i++) {
        int r = ty + i * 8;
        dst[(size_t)(nb + r) * K + kb + tx] = f2b(t[tx][r]);
    }
}

// ---------------- LayerNorm row (D=1024) f32 -> bf16 ----------------
__global__ __launch_bounds__(256) void ln_bf16(const float* __restrict__ x,
                                               const float* __restrict__ w,
                                               const float* __restrict__ b,
                                               u16* __restrict__ out) {
    int row = blockIdx.x, t = threadIdx.x;
    float4 v = ((const float4*)(x + (size_t)row * 1024))[t];
    float s1 = v.x + v.y + v.z + v.w;
    float s2 = v.x * v.x + v.y * v.y + v.z * v.z + v.w * v.w;
    for (int o = 32; o > 0; o >>= 1) { s1 += __shfl_xor(s1, o); s2 += __shfl_xor(s2, o); }
    __shared__ float a1[4], a2[4];
    if ((t & 63) == 0) { a1[t >> 6] = s1; a2[t >> 6] = s2; }
    __syncthreads();
    s1 = a1[0] + a1[1] + a1[2] + a1[3];
    s2 = a2[0] + a2[1] + a2[2] + a2[3];
    float mu = s1 * (1.0f / 1024.0f);
    float var = s2 * (1.0f / 1024.0f) - mu * mu;
    float rs = rsqrtf(var + EPS_);
    float4 wv = ((const float4*)w)[t];
    float4 bv = ((const float4*)b)[t];
    u16x4 o;
    o[0] = f2b((v.x - mu) * rs * wv.x + bv.x);
    o[1] = f2b((v.y - mu) * rs * wv.y + bv.y);
    o[2] = f2b((v.z - mu) * rs * wv.z + bv.z);
    o[3] = f2b((v.w - mu) * rs * wv.w + bv.w);
    ((u16x4*)(out + (size_t)row * 1024))[t] = o;
}

// ======== 8-phase 256x256 MFMA GEMM, BK=32, 4-deep K-tile pipeline ========
// MODE 0: qkv scatter (+bias, q pre-scaled)   MODE 2: outb = gelu(acc+bias), ld 4096
template <int MODE>
__global__ __launch_bounds__(512) void gemm256_8ph(
    const u16* __restrict__ A, const u16* __restrict__ Bt,
    const float* __restrict__ bias, int K,
    u16* __restrict__ outb,
    u16* __restrict__ qp, u16* __restrict__ kp, u16* __restrict__ vtp) {
    __shared__ u16 LS[4][2][256 * 32];   // 128 KiB
    int tid = threadIdx.x;
    int w = tid >> 6, lane = tid & 63, g = lane >> 4, ln = lane & 15;
    int wr = w >> 2, wc = w & 3;
    int gx = gridDim.x;
    int nwg = gx * gridDim.y;
    int lin = blockIdx.y * gx + blockIdx.x;
    int swz = (lin & 7) * (nwg >> 3) + (lin >> 3);
    int bx = swz % gx, by = swz / gx;
    int br = by * 256, bc = bx * 256;
    int jx = (((lane & 3) ^ ((lane >> 3) & 3)) << 3);
    const u16* Ast = A + (size_t)(br + w * 32 + (lane >> 2)) * K + jx;
    const u16* Bst = Bt + (size_t)(bc + w * 32 + (lane >> 2)) * K + jx;
    size_t r16 = (size_t)16 * K;
    const int ldsW = (w * 32) * 32;
    f32x4 acc[8][4] = {};
    int NT = K >> 5;
    int slotr = ((g ^ ((ln >> 1) & 3)) << 3);
    for (int kt = 0; kt < 3; ++kt) {
        glds16(Ast + (size_t)kt * 32, &LS[kt][0][ldsW]);
        glds16(Ast + (size_t)kt * 32 + r16, &LS[kt][0][ldsW + 512]);
        glds16(Bst + (size_t)kt * 32, &LS[kt][1][ldsW]);
        glds16(Bst + (size_t)kt * 32 + r16, &LS[kt][1][ldsW + 512]);
    }
    asm volatile("s_waitcnt vmcnt(8)" ::: "memory");
    __builtin_amdgcn_s_barrier();
    short8 aa[4], bb[4];
    for (int kt = 0; kt < NT; ++kt) {
        const u16* bufA = &LS[kt & 3][0][0];
        const u16* bufB = &LS[kt & 3][1][0];
        int s3 = kt + 3;
        #pragma unroll
        for (int m = 0; m < 4; ++m)
            aa[m] = *(const short8*)&bufA[(wr * 128 + m * 16 + ln) * 32 + slotr];
        #pragma unroll
        for (int n = 0; n < 4; ++n)
            bb[n] = *(const short8*)&bufB[(wc * 64 + n * 16 + ln) * 32 + slotr];
        if (s3 < NT) {
            u16* d = &LS[s3 & 3][0][ldsW];
            glds16(Ast + (size_t)s3 * 32, d);
            glds16(Ast + (size_t)s3 * 32 + r16, d + 512);
        }
        __builtin_amdgcn_s_barrier();
        asm volatile("s_waitcnt lgkmcnt(0)" ::: "memory");
        __builtin_amdgcn_sched_barrier(0);
        __builtin_amdgcn_s_setprio(1);
        #pragma unroll
        for (int m = 0; m < 4; ++m)
            #pragma unroll
            for (int n = 0; n < 4; ++n)
                acc[m][n] = __builtin_amdgcn_mfma_f32_16x16x32_bf16(aa[m], bb[n], acc[m][n], 0, 0, 0);
        __builtin_amdgcn_s_setprio(0);
        __builtin_amdgcn_sched_barrier(0);
        __builtin_amdgcn_s_barrier();
        #pragma unroll
        for (int m = 0; m < 4; ++m)
            aa[m] = *(const short8*)&bufA[(wr * 128 + 64 + m * 16 + ln) * 32 + slotr];
        if (s3 < NT) {
            u16* d = &LS[s3 & 3][1][ldsW];
            glds16(Bst + (size_t)s3 * 32, d);
            glds16(Bst + (size_t)s3 * 32 + r16, d + 512);
        }
        if (kt + 3 < NT)      asm volatile("s_waitcnt vmcnt(8)" ::: "memory");
        else if (kt + 2 < NT) asm volatile("s_waitcnt vmcnt(4)" ::: "memory");
        else if (kt + 1 < NT) asm volatile("s_waitcnt vmcnt(0)" ::: "memory");
        __builtin_amdgcn_s_barrier();
        asm volatile("s_waitcnt lgkmcnt(0)" ::: "memory");
        __builtin_amdgcn_sched_barrier(0);
        __builtin_amdgcn_s_setprio(1);
        #pragma unroll
        for (int m = 0; m < 4; ++m)
            #pragma unroll
            for (int n = 0; n < 4; ++n)
                acc[4 + m][n] = __builtin_amdgcn_mfma_f32_16x16x32_bf16(aa[m], bb[n], acc[4 + m][n], 0, 0, 0);
        __builtin_amdgcn_s_setprio(0);
        __builtin_amdgcn_sched_barrier(0);
        __builtin_amdgcn_s_barrier();
    }
    #pragma unroll
    for (int m = 0; m < 8; ++m) {
        int row0 = br + wr * 128 + m * 16 + g * 4;
        #pragma unroll
        for (int n = 0; n < 4; ++n) {
            int col = bc + wc * 64 + n * 16 + ln;
            float bv = bias[col];
            if constexpr (MODE == 0) {
                int which = col >> 10, cc = col & 1023, hh = cc >> 6, dh = cc & 63;
                int bb2 = row0 >> 11, nn0 = row0 & 2047;
                size_t bh = (size_t)(bb2 * 16 + hh);
                if (which == 0) {
                    for (int r = 0; r < 4; r++)
                        qp[((bh * 2048 + nn0 + r) << 6) + dh] = f2b((acc[m][n][r] + bv) * SC2_);
                } else if (which == 1) {
                    for (int r = 0; r < 4; r++)
                        kp[((bh * 2048 + nn0 + r) << 6) + dh] = f2b(acc[m][n][r] + bv);
                } else {
                    u16x4 o;
                    for (int r = 0; r < 4; r++) o[r] = f2b(acc[m][n][r] + bv);
                    *(u16x4*)&vtp[((bh * 64 + dh) << 11) + nn0] = o;
                }
            } else {
                for (int r = 0; r < 4; r++) {
                    float v = acc[m][n][r] + bv;
                    float gl = 0.5f * v * (1.0f + erff(v * 0.7071067811865476f));
                    outb[(size_t)(row0 + r) * 4096 + col] = f2b(gl);
                }
            }
        }
    }
}

// ---------------- bf16 GEMM (R8 structure): MODE 1: out=res+acc+b  MODE 3: out+=acc+b ----
template <int MODE, int BN>
__global__ __launch_bounds__(256) void gemm_bf16(
    const u16* __restrict__ A, const u16* __restrict__ Bt,
    const float* __restrict__ bias, int M, int N, int K,
    const float* __restrict__ res, float* __restrict__ outf) {
    constexpr int NN = BN / 32;
    __shared__ u16 As[128 * 64];
    __shared__ u16 Bs[BN * 64];
    int br = blockIdx.y * 128, bc = blockIdx.x * BN;
    int tid = threadIdx.x;
    int w = tid >> 6, lane = tid & 63, g = lane >> 4, ln = lane & 15;
    int wr = (w >> 1) * 64, wc = (w & 1) * (BN / 2);
    f32x4 acc[4][NN] = {};
    int sgcol = (((lane & 7) ^ (lane >> 3)) << 3);
    int arow = w * 32 + (lane >> 3);
    int brow = w * (BN / 4) + (lane >> 3);
    const u16* Ap = A + (size_t)(br + arow) * K + sgcol;
    const u16* Bp = Bt + (size_t)(bc + brow) * K + sgcol;
    u16* lA = &As[(w * 32) * 64];
    u16* lB = &Bs[(w * (BN / 4)) * 64];
    size_t rstep = (size_t)8 * K;
    for (int kt = 0; kt < K; kt += 64) {
        __syncthreads();
        #pragma unroll
        for (int i = 0; i < 4; i++) glds16(Ap + kt + i * rstep, lA + i * 512);
        #pragma unroll
        for (int i = 0; i < BN / 32; i++) glds16(Bp + kt + i * rstep, lB + i * 512);
        __syncthreads();
        #pragma unroll
        for (int kk = 0; kk < 2; kk++) {
            int so = (((kk << 2) + g) ^ (ln & 7)) << 3;
            short8 af[4], bfr[NN];
            #pragma unroll
            for (int m = 0; m < 4; m++)  af[m]  = *(const short8*)&As[(wr + m * 16 + ln) * 64 + so];
            #pragma unroll
            for (int n = 0; n < NN; n++) bfr[n] = *(const short8*)&Bs[(wc + n * 16 + ln) * 64 + so];
            #pragma unroll
            for (int m = 0; m < 4; m++)
                #pragma unroll
                for (int n = 0; n < NN; n++)
                    acc[m][n] = __builtin_amdgcn_mfma_f32_16x16x32_bf16(af[m], bfr[n], acc[m][n], 0, 0, 0);
        }
    }
    #pragma unroll
    for (int m = 0; m < 4; m++) {
        int row0 = br + wr + m * 16 + g * 4;
        #pragma unroll
        for (int n = 0; n < NN; n++) {
            int col = bc + wc + n * 16 + ln;
            float bv = bias[col];
            if constexpr (MODE == 1) {
                for (int r = 0; r < 4; r++) {
                    size_t idx = (size_t)(row0 + r) * 1024 + col;
                    outf[idx] = res[idx] + acc[m][n][r] + bv;
                }
            } else {
                for (int r = 0; r < 4; r++) {
                    size_t idx = (size_t)(row0 + r) * 1024 + col;
                    outf[idx] = outf[idx] + acc[m][n][r] + bv;
                }
            }
        }
    }
}

// ======== flash attention: 32x32x16 MFMA, 8 waves = 4 q-subgrp x 2 kv-halves ========
// grid (16 q-tiles, 32 bh) x 512 thr. 128 q/block; wave (qs,kh): 32 q, kv half kh.
// q pre-scaled SCALE*LOG2E; dist raw f32 (LOG2E in gam). P in registers via
// cvt_pk + permlane32_swap (R5-validated mappings). K/V staged by glds16 with
// pre-swizzled source (slot ^ row&7). LDS merge of kv-halves at end.
__global__ __launch_bounds__(512, 4) void attn_fwd(
    const u16* __restrict__ qg, const u16* __restrict__ kg, const u16* __restrict__ vtg,
    const float* __restrict__ dist, const float* __restrict__ gamma, u16* __restrict__ ao) {
    __shared__ u16 Ks[2][2][64 * 64];   // [kh][buf][kv][d]  32 KB
    __shared__ u16 Vs[2][2][64 * 64];   // [kh][buf][d][kv]  32 KB
    int qt = blockIdx.x, bh = blockIdx.y;
    int b = bh >> 4, h16 = bh & 15;
    int tid = threadIdx.x, w = tid >> 6, lane = tid & 63;
    int kh = w >> 2, qs = w & 3;
    int ln = lane & 31, hh = lane >> 5;
    float gam = gamma[bh] * LOG2E_;
    int qglob = qt * 128 + qs * 32 + ln;
    const u16* qrow = qg + ((size_t)bh * 2048 + qglob) * 64;
    short8 qB[4];
    #pragma unroll
    for (int st = 0; st < 4; ++st) qB[st] = *(const short8*)(qrow + st * 16 + hh * 8);
    const float* drow = dist + (size_t)qglob * 2048 + kh * 1024 + hh * 4;
    // glds16 staging: wave (qs,kh) stages rows [qs*16, qs*16+16) of its half's K,V^T
    int l3 = lane >> 3, l7 = lane & 7;
    int swsl = ((l7 ^ (l3 & 7)) << 3);   // pre-swizzled source slot (u16 units)
    const u16* kbase = kg + ((size_t)(bh * 2048 + kh * 1024 + qs * 16 + l3)) * 64 + swsl;
    const u16* vbase = vtg + ((size_t)(bh * 64 + qs * 16 + l3)) * 2048 + kh * 1024 + swsl;
    u16* lk0 = &Ks[kh][0][(qs * 16) * 64]; u16* lk1 = &Ks[kh][1][(qs * 16) * 64];
    u16* lv0 = &Vs[kh][0][(qs * 16) * 64]; u16* lv1 = &Vs[kh][1][(qs * 16) * 64];
    glds16(kbase, lk0); glds16(kbase + 512, lk0 + 512);
    glds16(vbase, lv0); glds16(vbase + 16384, lv0 + 512);
    __syncthreads();
    float m2 = -3.0e38f, lsum = 0.0f;
    f32x16 acc0 = {}, acc1 = {};
    int cur = 0;
    for (int kt = 0; kt < 16; ++kt) {
        if (kt < 15) {   // stage next tile into other buffer (async; drained by syncthreads)
            const u16* kn = kbase + (size_t)(kt + 1) * 4096;
            const u16* vn = vbase + (size_t)(kt + 1) * 64;
            u16* dk = cur ? lk0 : lk1;
            u16* dv = cur ? lv0 : lv1;
            glds16(kn, dk); glds16(kn + 512, dk + 512);
            glds16(vn, dv); glds16(vn + 16384, dv + 512);
        }
        const u16* KB = &Ks[kh][cur][0];
        const u16* VB = &Vs[kh][cur][0];
        // QK^T: sa = K x Q^T, col = q (ln); sa0 = kv 0..31, sa1 = kv 32..63
        f32x16 sa0 = {}, sa1 = {};
        __builtin_amdgcn_s_setprio(1);
        #pragma unroll
        for (int st = 0; st < 4; ++st) {
            int so = (((st * 2 + hh) ^ (ln & 7)) << 3);
            short8 kf0 = *(const short8*)&KB[ln * 64 + so];
            short8 kf1 = *(const short8*)&KB[(32 + ln) * 64 + so];
            sa0 = __builtin_amdgcn_mfma_f32_32x32x16_bf16(kf0, qB[st], sa0, 0, 0, 0);
            sa1 = __builtin_amdgcn_mfma_f32_32x32x16_bf16(kf1, qB[st], sa1, 0, 0, 0);
        }
        __builtin_amdgcn_s_setprio(0);
        // bias + max (dist loads split to limit live range); sv overwrites sa
        const float* dt = drow + kt * 64;
        float pm = -3.0e38f;
        #pragma unroll
        for (int i = 0; i < 4; ++i) {
            f32x4 dv = *(const f32x4*)(dt + i * 8);
            sa0[i * 4 + 0] -= gam * dv[0];
            sa0[i * 4 + 1] -= gam * dv[1];
            sa0[i * 4 + 2] -= gam * dv[2];
            sa0[i * 4 + 3] -= gam * dv[3];
            pm = fmaxf(pm, fmaxf(fmaxf(sa0[i*4], sa0[i*4+1]), fmaxf(sa0[i*4+2], sa0[i*4+3])));
        }
        #pragma unroll
        for (int i = 0; i < 4; ++i) {
            f32x4 dv = *(const f32x4*)(dt + 32 + i * 8);
            sa1[i * 4 + 0] -= gam * dv[0];
            sa1[i * 4 + 1] -= gam * dv[1];
            sa1[i * 4 + 2] -= gam * dv[2];
            sa1[i * 4 + 3] -= gam * dv[3];
            pm = fmaxf(pm, fmaxf(fmaxf(sa1[i*4], sa1[i*4+1]), fmaxf(sa1[i*4+2], sa1[i*4+3])));
        }
        pm = fmaxf(pm, __shfl_xor(pm, 32));
        if (!__all(pm - m2 <= 8.0f)) {   // defer-max
            float nm = fmaxf(m2, pm);
            float al = __builtin_exp2f(m2 - nm);
            m2 = nm;
            lsum *= al;
            acc0 *= al; acc1 *= al;
        }
        float ps = 0.0f;
        #pragma unroll
        for (int r = 0; r < 16; ++r) {
            sa0[r] = __builtin_exp2f(sa0[r] - m2); ps += sa0[r];
            sa1[r] = __builtin_exp2f(sa1[r] - m2); ps += sa1[r];
        }
        lsum += ps;   // per-hh partial; combined after loop
        // P -> bf16 B-frags in-register (R5-validated)
        unsigned w0[8], w1[8];
        #pragma unroll
        for (int qr = 0; qr < 4; ++qr) {
            w0[qr * 2]     = cvtpk(sa0[qr * 4], sa0[qr * 4 + 1]);
            w0[qr * 2 + 1] = cvtpk(sa0[qr * 4 + 2], sa0[qr * 4 + 3]);
            w1[qr * 2]     = cvtpk(sa1[qr * 4], sa1[qr * 4 + 1]);
            w1[qr * 2 + 1] = cvtpk(sa1[qr * 4 + 2], sa1[qr * 4 + 3]);
        }
        pl32swap(w0[0], w0[2]); pl32swap(w0[1], w0[3]);
        pl32swap(w0[4], w0[6]); pl32swap(w0[5], w0[7]);
        pl32swap(w1[0], w1[2]); pl32swap(w1[1], w1[3]);
        pl32swap(w1[4], w1[6]); pl32swap(w1[5], w1[7]);
        short8 pB[4];
        pB[0] = mk8(w0[0], w0[1], w0[2], w0[3]);
        pB[1] = mk8(w0[4], w0[5], w0[6], w0[7]);
        pB[2] = mk8(w1[0], w1[1], w1[2], w1[3]);
        pB[3] = mk8(w1[4], w1[5], w1[6], w1[7]);
        // PV: acc += V^T x P^T
        __builtin_amdgcn_s_setprio(1);
        #pragma unroll
        for (int sg = 0; sg < 4; ++sg) {
            int so = (((sg * 2 + hh) ^ (ln & 7)) << 3);
            short8 vf0 = *(const short8*)&VB[ln * 64 + so];
            short8 vf1 = *(const short8*)&VB[(32 + ln) * 64 + so];
            acc0 = __builtin_amdgcn_mfma_f32_32x32x16_bf16(vf0, pB[sg], acc0, 0, 0, 0);
            acc1 = __builtin_amdgcn_mfma_f32_32x32x16_bf16(vf1, pB[sg], acc1, 0, 0, 0);
        }
        __builtin_amdgcn_s_setprio(0);
        __syncthreads();   // drains glds16 (vmcnt) + ds reads (lgkm)
        cur ^= 1;
    }
    lsum += __shfl_xor(lsum, 32);
    // merge kv-halves via LDS (reuse Ks/Vs space; all reads done at last barrier)
    float* mrg = (float*)&Ks[0][0][0];   // [qs][lane][32 acc | m | l] = 34 KB
    if (kh == 1) {
        float* p = mrg + (size_t)(qs * 64 + lane) * 34;
        #pragma unroll
        for (int r = 0; r < 16; ++r) { p[r] = acc0[r]; p[16 + r] = acc1[r]; }
        p[32] = m2; p[33] = lsum;
    }
    __syncthreads();
    if (kh == 0) {
        const float* p = mrg + (size_t)(qs * 64 + lane) * 34;
        float m1 = p[32], l1 = p[33];
        float M = fmaxf(m2, m1);
        float s0 = __builtin_exp2f(m2 - M);
        float s1 = __builtin_exp2f(m1 - M);
        float inv = 1.0f / (lsum * s0 + l1 * s1);
        u16* aop = ao + ((size_t)(b * 2048 + qglob)) * 1024 + h16 * 64 + hh * 4;
        #pragma unroll
        for (int qr = 0; qr < 4; ++qr) {
            u16x4 o0, o1;
            #pragma unroll
            for (int r = 0; r < 4; ++r) {
                o0[r] = f2b((acc0[qr * 4 + r] * s0 + p[qr * 4 + r] * s1) * inv);
                o1[r] = f2b((acc1[qr * 4 + r] * s0 + p[16 + qr * 4 + r] * s1) * inv);
            }
            *(u16x4*)(aop + qr * 8) = o0;
            *(u16x4*)(aop + 32 + qr * 8) = o1;
        }
    }
}

extern "C" void kernel_launch(void* const* d_in, const int* in_sizes, int n_in,
                              void* d_out, int out_size, void* d_ws, size_t ws_size,
                              hipStream_t stream) {
    const float* x     = (const float*)d_in[0];
    const float* gamma = (const float*)d_in[1];
    const float* dist  = (const float*)d_in[2];
    const float* ln1w  = (const float*)d_in[3];
    const float* ln1b  = (const float*)d_in[4];
    const float* qkvw  = (const float*)d_in[5];
    const float* qkvb  = (const float*)d_in[6];
    const float* projw = (const float*)d_in[7];
    const float* projb = (const float*)d_in[8];
    const float* ln2w  = (const float*)d_in[9];
    const float* ln2b  = (const float*)d_in[10];
    const float* w1    = (const float*)d_in[11];
    const float* b1    = (const float*)d_in[12];
    const float* w2    = (const float*)d_in[13];
    const float* b2    = (const float*)d_in[14];
    float* out = (float*)d_out;
    char* ws = (char*)d_ws;
    u16* wqkvT  = (u16*)(ws + 0);
    u16* wprojT = (u16*)(ws + 6291456);
    u16* w1T    = (u16*)(ws + 8388608);
    u16* w2T    = (u16*)(ws + 16777216);
    u16* hb     = (u16*)(ws + 33554432);
    u16* qb     = (u16*)(ws + 41943040);
    u16* kb     = (u16*)(ws + 50331648);
    u16* vtb    = (u16*)(ws + 58720256);
    u16* aob    = (u16*)(ws + 67108864);
    u16* gb     = hb;    // mlp1 output reuses h..vT region (dead by then)
    u16* h2b    = aob;   // ln2 output reuses ao slot (dead after proj)

    dim3 blk(256);
    transpose_cast<<<dim3(3072 / 32, 1024 / 32), blk, 0, stream>>>(qkvw, wqkvT, 1024, 3072);
    transpose_cast<<<dim3(1024 / 32, 1024 / 32), blk, 0, stream>>>(projw, wprojT, 1024, 1024);
    transpose_cast<<<dim3(4096 / 32, 1024 / 32), blk, 0, stream>>>(w1, w1T, 1024, 4096);
    transpose_cast<<<dim3(1024 / 32, 4096 / 32), blk, 0, stream>>>(w2, w2T, 4096, 1024);
    ln_bf16<<<4096, blk, 0, stream>>>(x, ln1w, ln1b, hb);
    gemm256_8ph<0><<<dim3(12, 16), dim3(512), 0, stream>>>(hb, wqkvT, qkvb, 1024,
                                                           nullptr, qb, kb, vtb);
    attn_fwd<<<dim3(16, 32), dim3(512), 0, stream>>>(qb, kb, vtb, dist, gamma, aob);
    gemm_bf16<1, 64><<<dim3(16, 32), blk, 0, stream>>>(aob, wprojT, projb, 4096, 1024, 1024,
                                                       x, out);
    ln_bf16<<<4096, blk, 0, stream>>>(out, ln2w, ln2b, h2b);
    gemm256_8ph<2><<<dim3(16, 16), dim3(512), 0, stream>>>(h2b, w1T, b1, 1024,
                                                           gb, nullptr, nullptr, nullptr);
    gemm_bf16<3, 64><<<dim3(16, 32), blk, 0, stream>>>(gb, w2T, b2, 4096, 1024, 4096,
                                                       nullptr, out);
}

// Round 11
// 262.175 us; speedup vs baseline: 1.1173x; 1.1133x over previous
//
#include <hip/hip_runtime.h>
#include <hip/hip_bf16.h>

// ZoomTransformerBlock: B=2, N=2048, D=1024, H=16, DH=64, DF=4096
// R11: attn reverted to R9 (16x16, 8-wave, f32 dist; 87us measured);
//      mlp2 -> 8-phase 256^2 split-K=4 with PRIVATE bf16 partial buffers
//      (no atomics) + combine kernel (out += sum(partials) + bias).
//      Partials live in workspace regions dead by mlp2 time.

#define SCALE_ 0.03125f   // D^-0.5 = 1/32
#define EPS_   1e-5f
#define LOG2E_ 1.4426950408889634f
#define SC2_   (SCALE_ * LOG2E_)

typedef unsigned short u16;
typedef __attribute__((ext_vector_type(8))) short short8;
typedef __attribute__((ext_vector_type(4))) float f32x4;
typedef __attribute__((ext_vector_type(4))) unsigned short u16x4;

__device__ inline float b2f(u16 u){ unsigned x = ((unsigned)u) << 16; float f; __builtin_memcpy(&f, &x, 4); return f; }
__device__ inline u16 f2b(float f){ __hip_bfloat16 h = __float2bfloat16(f); u16 u; __builtin_memcpy(&u, &h, 2); return u; }

// async global->LDS, 16B per lane; LDS dest = wave-uniform base + lane*16 (linear)
__device__ inline void glds16(const u16* g, u16* l) {
    __builtin_amdgcn_global_load_lds(
        (const __attribute__((address_space(1))) void*)g,
        (__attribute__((address_space(3))) void*)l, 16, 0, 0);
}

// pack 2 f32 -> 1 dword of 2 bf16 (lo = a, hi = b)
__device__ inline unsigned cvtpk(float a, float b) {
    unsigned r;
    asm("v_cvt_pk_bf16_f32 %0, %1, %2" : "=v"(r) : "v"(a), "v"(b));
    return r;
}

// ---------------- transpose + cast: src [K][N] f32 -> dst [N][K] bf16 ----------------
__global__ __launch_bounds__(256) void transpose_cast(const float* __restrict__ src,
                                                      u16* __restrict__ dst, int K, int N) {
    __shared__ float t[32][33];
    int nb = blockIdx.x * 32, kb = blockIdx.y * 32;
    int tx = threadIdx.x & 31, ty = threadIdx.x >> 5;
    for (int i = 0; i < 4; i++) {
        int r = ty + i * 8;
        t[r][tx] = src[(size_t)(kb + r) * N + nb + tx];
    }
    __syncthreads();
    for (int i = 0; i < 4; i++) {
        int r = ty + i * 8;
        dst[(size_t)(nb + r) * K + kb + tx] = f2b(t[tx][r]);
    }
}

// ---------------- LayerNorm row (D=1024) f32 -> bf16 ----------------
__global__ __launch_bounds__(256) void ln_bf16(const float* __restrict__ x,
                                               const float* __restrict__ w,
                                               const float* __restrict__ b,
                                               u16* __restrict__ out) {
    int row = blockIdx.x, t = threadIdx.x;
    float4 v = ((const float4*)(x + (size_t)row * 1024))[t];
    float s1 = v.x + v.y + v.z + v.w;
    float s2 = v.x * v.x + v.y * v.y + v.z * v.z + v.w * v.w;
    for (int o = 32; o > 0; o >>= 1) { s1 += __shfl_xor(s1, o); s2 += __shfl_xor(s2, o); }
    __shared__ float a1[4], a2[4];
    if ((t & 63) == 0) { a1[t >> 6] = s1; a2[t >> 6] = s2; }
    __syncthreads();
    s1 = a1[0] + a1[1] + a1[2] + a1[3];
    s2 = a2[0] + a2[1] + a2[2] + a2[3];
    float mu = s1 * (1.0f / 1024.0f);
    float var = s2 * (1.0f / 1024.0f) - mu * mu;
    float rs = rsqrtf(var + EPS_);
    float4 wv = ((const float4*)w)[t];
    float4 bv = ((const float4*)b)[t];
    u16x4 o;
    o[0] = f2b((v.x - mu) * rs * wv.x + bv.x);
    o[1] = f2b((v.y - mu) * rs * wv.y + bv.y);
    o[2] = f2b((v.z - mu) * rs * wv.z + bv.z);
    o[3] = f2b((v.w - mu) * rs * wv.w + bv.w);
    ((u16x4*)(out + (size_t)row * 1024))[t] = o;
}

// ---------------- combine: out += b2f(p0..p3) + bias   (mlp2 split-K merge) ----------------
__global__ __launch_bounds__(256) void combine4(
    const u16* __restrict__ p0, const u16* __restrict__ p1,
    const u16* __restrict__ p2, const u16* __restrict__ p3,
    const float* __restrict__ bias, float* __restrict__ out) {
    size_t i = (size_t)(blockIdx.x * 256 + threadIdx.x) * 4;   // grid covers 4096*1024/4
    u16x4 a0 = *(const u16x4*)(p0 + i);
    u16x4 a1 = *(const u16x4*)(p1 + i);
    u16x4 a2 = *(const u16x4*)(p2 + i);
    u16x4 a3 = *(const u16x4*)(p3 + i);
    float4 ov = *(float4*)(out + i);
    float4 bv = *(const float4*)(bias + (i & 1023));
    ov.x += b2f(a0[0]) + b2f(a1[0]) + b2f(a2[0]) + b2f(a3[0]) + bv.x;
    ov.y += b2f(a0[1]) + b2f(a1[1]) + b2f(a2[1]) + b2f(a3[1]) + bv.y;
    ov.z += b2f(a0[2]) + b2f(a1[2]) + b2f(a2[2]) + b2f(a3[2]) + bv.z;
    ov.w += b2f(a0[3]) + b2f(a1[3]) + b2f(a2[3]) + b2f(a3[3]) + bv.w;
    *(float4*)(out + i) = ov;
}

// ======== 8-phase 256x256 MFMA GEMM, BK=32, 4-deep K-tile pipeline ========
// MODE 0: qkv scatter (+bias, q pre-scaled)   MODE 2: outb = gelu(acc+bias), ld 4096
// MODE 3: bf16 partial per K-split (z), ld 1024; buffers: outb,qp,kp,vtp = p0..p3
template <int MODE>
__global__ __launch_bounds__(512) void gemm256_8ph(
    const u16* __restrict__ A, const u16* __restrict__ Bt,
    const float* __restrict__ bias, int K, int ksl,
    u16* __restrict__ outb,
    u16* __restrict__ qp, u16* __restrict__ kp, u16* __restrict__ vtp) {
    __shared__ u16 LS[4][2][256 * 32];   // 128 KiB
    int tid = threadIdx.x;
    int w = tid >> 6, lane = tid & 63, g = lane >> 4, ln = lane & 15;
    int wr = w >> 2, wc = w & 3;
    int gx = gridDim.x;
    int nwg = gx * gridDim.y;
    int lin = blockIdx.y * gx + blockIdx.x;
    int swz = (lin & 7) * (nwg >> 3) + (lin >> 3);
    int bx = swz % gx, by = swz / gx;
    int br = by * 256, bc = bx * 256;
    int k0 = blockIdx.z * ksl;
    int jx = (((lane & 3) ^ ((lane >> 3) & 3)) << 3);
    const u16* Ast = A + (size_t)(br + w * 32 + (lane >> 2)) * K + k0 + jx;
    const u16* Bst = Bt + (size_t)(bc + w * 32 + (lane >> 2)) * K + k0 + jx;
    size_t r16 = (size_t)16 * K;
    const int ldsW = (w * 32) * 32;
    f32x4 acc[8][4] = {};
    int NT = ksl >> 5;
    int slotr = ((g ^ ((ln >> 1) & 3)) << 3);
    for (int kt = 0; kt < 3; ++kt) {
        glds16(Ast + (size_t)kt * 32, &LS[kt][0][ldsW]);
        glds16(Ast + (size_t)kt * 32 + r16, &LS[kt][0][ldsW + 512]);
        glds16(Bst + (size_t)kt * 32, &LS[kt][1][ldsW]);
        glds16(Bst + (size_t)kt * 32 + r16, &LS[kt][1][ldsW + 512]);
    }
    asm volatile("s_waitcnt vmcnt(8)" ::: "memory");
    __builtin_amdgcn_s_barrier();
    short8 aa[4], bb[4];
    for (int kt = 0; kt < NT; ++kt) {
        const u16* bufA = &LS[kt & 3][0][0];
        const u16* bufB = &LS[kt & 3][1][0];
        int s3 = kt + 3;
        #pragma unroll
        for (int m = 0; m < 4; ++m)
            aa[m] = *(const short8*)&bufA[(wr * 128 + m * 16 + ln) * 32 + slotr];
        #pragma unroll
        for (int n = 0; n < 4; ++n)
            bb[n] = *(const short8*)&bufB[(wc * 64 + n * 16 + ln) * 32 + slotr];
        if (s3 < NT) {
            u16* d = &LS[s3 & 3][0][ldsW];
            glds16(Ast + (size_t)s3 * 32, d);
            glds16(Ast + (size_t)s3 * 32 + r16, d + 512);
        }
        __builtin_amdgcn_s_barrier();
        asm volatile("s_waitcnt lgkmcnt(0)" ::: "memory");
        __builtin_amdgcn_sched_barrier(0);
        __builtin_amdgcn_s_setprio(1);
        #pragma unroll
        for (int m = 0; m < 4; ++m)
            #pragma unroll
            for (int n = 0; n < 4; ++n)
                acc[m][n] = __builtin_amdgcn_mfma_f32_16x16x32_bf16(aa[m], bb[n], acc[m][n], 0, 0, 0);
        __builtin_amdgcn_s_setprio(0);
        __builtin_amdgcn_sched_barrier(0);
        __builtin_amdgcn_s_barrier();
        #pragma unroll
        for (int m = 0; m < 4; ++m)
            aa[m] = *(const short8*)&bufA[(wr * 128 + 64 + m * 16 + ln) * 32 + slotr];
        if (s3 < NT) {
            u16* d = &LS[s3 & 3][1][ldsW];
            glds16(Bst + (size_t)s3 * 32, d);
            glds16(Bst + (size_t)s3 * 32 + r16, d + 512);
        }
        if (kt + 3 < NT)      asm volatile("s_waitcnt vmcnt(8)" ::: "memory");
        else if (kt + 2 < NT) asm volatile("s_waitcnt vmcnt(4)" ::: "memory");
        else if (kt + 1 < NT) asm volatile("s_waitcnt vmcnt(0)" ::: "memory");
        __builtin_amdgcn_s_barrier();
        asm volatile("s_waitcnt lgkmcnt(0)" ::: "memory");
        __builtin_amdgcn_sched_barrier(0);
        __builtin_amdgcn_s_setprio(1);
        #pragma unroll
        for (int m = 0; m < 4; ++m)
            #pragma unroll
            for (int n = 0; n < 4; ++n)
                acc[4 + m][n] = __builtin_amdgcn_mfma_f32_16x16x32_bf16(aa[m], bb[n], acc[4 + m][n], 0, 0, 0);
        __builtin_amdgcn_s_setprio(0);
        __builtin_amdgcn_sched_barrier(0);
        __builtin_amdgcn_s_barrier();
    }
    #pragma unroll
    for (int m = 0; m < 8; ++m) {
        int row0 = br + wr * 128 + m * 16 + g * 4;
        #pragma unroll
        for (int n = 0; n < 4; ++n) {
            int col = bc + wc * 64 + n * 16 + ln;
            if constexpr (MODE == 0) {
                float bv = bias[col];
                int which = col >> 10, cc = col & 1023, hh = cc >> 6, dh = cc & 63;
                int bb2 = row0 >> 11, nn0 = row0 & 2047;
                size_t bh = (size_t)(bb2 * 16 + hh);
                if (which == 0) {
                    for (int r = 0; r < 4; r++)
                        qp[((bh * 2048 + nn0 + r) << 6) + dh] = f2b((acc[m][n][r] + bv) * SC2_);
                } else if (which == 1) {
                    for (int r = 0; r < 4; r++)
                        kp[((bh * 2048 + nn0 + r) << 6) + dh] = f2b(acc[m][n][r] + bv);
                } else {
                    u16x4 o;
                    for (int r = 0; r < 4; r++) o[r] = f2b(acc[m][n][r] + bv);
                    *(u16x4*)&vtp[((bh * 64 + dh) << 11) + nn0] = o;
                }
            } else if constexpr (MODE == 2) {
                float bv = bias[col];
                for (int r = 0; r < 4; r++) {
                    float v = acc[m][n][r] + bv;
                    float gl = 0.5f * v * (1.0f + erff(v * 0.7071067811865476f));
                    outb[(size_t)(row0 + r) * 4096 + col] = f2b(gl);
                }
            } else {   // MODE 3: bf16 partial (no bias; combine adds it)
                u16* pb = (blockIdx.z == 0) ? outb : (blockIdx.z == 1) ? qp
                        : (blockIdx.z == 2) ? kp : vtp;
                for (int r = 0; r < 4; r++)
                    pb[(size_t)(row0 + r) * 1024 + col] = f2b(acc[m][n][r]);
            }
        }
    }
}

// ---------------- bf16 GEMM (R8 structure): MODE 1: out = res + acc + bias ----------------
template <int MODE, int BN>
__global__ __launch_bounds__(256) void gemm_bf16(
    const u16* __restrict__ A, const u16* __restrict__ Bt,
    const float* __restrict__ bias, int M, int N, int K,
    const float* __restrict__ res, float* __restrict__ outf) {
    constexpr int NN = BN / 32;
    __shared__ u16 As[128 * 64];
    __shared__ u16 Bs[BN * 64];
    int br = blockIdx.y * 128, bc = blockIdx.x * BN;
    int tid = threadIdx.x;
    int w = tid >> 6, lane = tid & 63, g = lane >> 4, ln = lane & 15;
    int wr = (w >> 1) * 64, wc = (w & 1) * (BN / 2);
    f32x4 acc[4][NN] = {};
    int sgcol = (((lane & 7) ^ (lane >> 3)) << 3);
    int arow = w * 32 + (lane >> 3);
    int brow = w * (BN / 4) + (lane >> 3);
    const u16* Ap = A + (size_t)(br + arow) * K + sgcol;
    const u16* Bp = Bt + (size_t)(bc + brow) * K + sgcol;
    u16* lA = &As[(w * 32) * 64];
    u16* lB = &Bs[(w * (BN / 4)) * 64];
    size_t rstep = (size_t)8 * K;
    for (int kt = 0; kt < K; kt += 64) {
        __syncthreads();
        #pragma unroll
        for (int i = 0; i < 4; i++) glds16(Ap + kt + i * rstep, lA + i * 512);
        #pragma unroll
        for (int i = 0; i < BN / 32; i++) glds16(Bp + kt + i * rstep, lB + i * 512);
        __syncthreads();
        #pragma unroll
        for (int kk = 0; kk < 2; kk++) {
            int so = (((kk << 2) + g) ^ (ln & 7)) << 3;
            short8 af[4], bfr[NN];
            #pragma unroll
            for (int m = 0; m < 4; m++)  af[m]  = *(const short8*)&As[(wr + m * 16 + ln) * 64 + so];
            #pragma unroll
            for (int n = 0; n < NN; n++) bfr[n] = *(const short8*)&Bs[(wc + n * 16 + ln) * 64 + so];
            #pragma unroll
            for (int m = 0; m < 4; m++)
                #pragma unroll
                for (int n = 0; n < NN; n++)
                    acc[m][n] = __builtin_amdgcn_mfma_f32_16x16x32_bf16(af[m], bfr[n], acc[m][n], 0, 0, 0);
        }
    }
    #pragma unroll
    for (int m = 0; m < 4; m++) {
        int row0 = br + wr + m * 16 + g * 4;
        #pragma unroll
        for (int n = 0; n < NN; n++) {
            int col = bc + wc + n * 16 + ln;
            float bv = bias[col];
            for (int r = 0; r < 4; r++) {
                size_t idx = (size_t)(row0 + r) * 1024 + col;
                outf[idx] = res[idx] + acc[m][n][r] + bv;
            }
        }
    }
}

// ---------------- flash attention: 8 waves (QBLK=128), swapped QK^T, dbuf LDS ----------------
// grid (16 q-tiles, 32 bh), 8 waves/wg; q pre-scaled by SCALE*LOG2E; dist raw f32.
__global__ __launch_bounds__(512) void attn_fwd(
    const u16* __restrict__ qg, const u16* __restrict__ kg, const u16* __restrict__ vtg,
    const float* __restrict__ dist, const float* __restrict__ gamma, u16* __restrict__ ao) {
    __shared__ u16 Ks[2][64 * 64];   // 16 KB
    __shared__ u16 Vs[2][64 * 64];   // 16 KB (V^T)
    __shared__ u16 Ps[8][16 * 64];   // 16 KB
    int qt = blockIdx.x, bh = blockIdx.y;
    int b = bh >> 4, h = bh & 15;
    int tid = threadIdx.x, w = tid >> 6, lane = tid & 63, g = lane >> 4, ln = lane & 15;
    float gam = gamma[bh] * LOG2E_;
    int qglob = qt * 128 + w * 16 + ln;
    const u16* qrow = qg + ((size_t)bh * 2048 + qglob) * 64;
    short8 qf0 = *(const short8*)(qrow + g * 8);
    short8 qf1 = *(const short8*)(qrow + 32 + g * 8);
    const float* dbase = dist + (size_t)qglob * 2048 + g * 4;
    float m2 = -3.0e38f, lsum = 0.0f;
    f32x4 acco[4] = {};
    int srow = tid >> 3, seg = tid & 7;
    int ss = ((seg ^ (srow & 7)) << 3);
    const u16* kgp = kg + ((size_t)bh * 2048 + srow) * 64 + seg * 8;
    const u16* vgp = vtg + ((size_t)bh * 64 + srow) * 2048 + seg * 8;
    {   // prologue: tile 0
        short8 a0 = *(const short8*)(kgp);
        short8 c0 = *(const short8*)(vgp);
        *(short8*)&Ks[0][srow * 64 + ss] = a0;
        *(short8*)&Vs[0][srow * 64 + ss] = c0;
    }
    f32x4 dcv[4];
    #pragma unroll
    for (int nb = 0; nb < 4; nb++) dcv[nb] = *(const f32x4*)(dbase + nb * 16);
    __syncthreads();
    int cur = 0;
    int so0 = (g ^ (ln & 7)) << 3, so1 = ((4 + g) ^ (ln & 7)) << 3;
    for (int kt = 0; kt < 32; kt++) {
        short8 kr0, vr0;
        f32x4 dnx[4];
        if (kt < 31) {
            kr0 = *(const short8*)(kgp + (kt + 1) * 4096);
            vr0 = *(const short8*)(vgp + (kt + 1) * 64);
            #pragma unroll
            for (int nb = 0; nb < 4; nb++)
                dnx[nb] = *(const f32x4*)(dbase + (kt + 1) * 64 + nb * 16);
        }
        f32x4 sa[4] = {};
        __builtin_amdgcn_s_setprio(1);
        #pragma unroll
        for (int nb = 0; nb < 4; nb++) {
            short8 kf0 = *(const short8*)&Ks[cur][(nb * 16 + ln) * 64 + so0];
            short8 kf1 = *(const short8*)&Ks[cur][(nb * 16 + ln) * 64 + so1];
            sa[nb] = __builtin_amdgcn_mfma_f32_16x16x32_bf16(kf0, qf0, sa[nb], 0, 0, 0);
            sa[nb] = __builtin_amdgcn_mfma_f32_16x16x32_bf16(kf1, qf1, sa[nb], 0, 0, 0);
        }
        __builtin_amdgcn_s_setprio(0);
        float sv[4][4], pm = -3.0e38f;
        #pragma unroll
        for (int nb = 0; nb < 4; nb++) {
            #pragma unroll
            for (int r = 0; r < 4; r++)
                sv[nb][r] = sa[nb][r] - gam * dcv[nb][r];
            pm = fmaxf(pm, fmaxf(fmaxf(sv[nb][0], sv[nb][1]), fmaxf(sv[nb][2], sv[nb][3])));
        }
        pm = fmaxf(pm, __shfl_xor(pm, 16));
        pm = fmaxf(pm, __shfl_xor(pm, 32));
        if (!__all(pm - m2 <= 8.0f)) {
            float nm = fmaxf(m2, pm);
            float al = __builtin_exp2f(m2 - nm);
            m2 = nm;
            lsum *= al;
            #pragma unroll
            for (int db = 0; db < 4; db++) acco[db] *= al;
        }
        float ps = 0.0f;
        #pragma unroll
        for (int nb = 0; nb < 4; nb++) {
            float e0 = __builtin_exp2f(sv[nb][0] - m2);
            float e1 = __builtin_exp2f(sv[nb][1] - m2);
            float e2 = __builtin_exp2f(sv[nb][2] - m2);
            float e3 = __builtin_exp2f(sv[nb][3] - m2);
            ps += (e0 + e1) + (e2 + e3);
            union { unsigned u[2]; u16x4 v; } pk;
            pk.u[0] = cvtpk(e0, e1);
            pk.u[1] = cvtpk(e2, e3);
            int off = nb * 16 + g * 4;
            *(u16x4*)&Ps[w][ln * 64 + (((off >> 3) ^ (ln & 7)) << 3) + (off & 7)] = pk.v;
        }
        ps += __shfl_xor(ps, 16);
        ps += __shfl_xor(ps, 32);
        lsum += ps;
        short8 pf0 = *(const short8*)&Ps[w][ln * 64 + so0];
        short8 pf1 = *(const short8*)&Ps[w][ln * 64 + so1];
        __builtin_amdgcn_s_setprio(1);
        #pragma unroll
        for (int db = 0; db < 4; db++) {
            short8 vf0 = *(const short8*)&Vs[cur][(db * 16 + ln) * 64 + so0];
            short8 vf1 = *(const short8*)&Vs[cur][(db * 16 + ln) * 64 + so1];
            acco[db] = __builtin_amdgcn_mfma_f32_16x16x32_bf16(vf0, pf0, acco[db], 0, 0, 0);
            acco[db] = __builtin_amdgcn_mfma_f32_16x16x32_bf16(vf1, pf1, acco[db], 0, 0, 0);
        }
        __builtin_amdgcn_s_setprio(0);
        if (kt < 31) {
            int nx = cur ^ 1;
            *(short8*)&Ks[nx][srow * 64 + ss] = kr0;
            *(short8*)&Vs[nx][srow * 64 + ss] = vr0;
            #pragma unroll
            for (int nb = 0; nb < 4; nb++) dcv[nb] = dnx[nb];
            __syncthreads();
            cur = nx;
        }
    }
    float inv = 1.0f / lsum;
    u16* aop = ao + (size_t)(b * 2048 + qglob) * 1024 + h * 64 + g * 4;
    #pragma unroll
    for (int db = 0; db < 4; db++) {
        u16x4 o;
        #pragma unroll
        for (int r = 0; r < 4; r++) o[r] = f2b(acco[db][r] * inv);
        *(u16x4*)(aop + db * 16) = o;
    }
}

extern "C" void kernel_launch(void* const* d_in, const int* in_sizes, int n_in,
                              void* d_out, int out_size, void* d_ws, size_t ws_size,
                              hipStream_t stream) {
    const float* x     = (const float*)d_in[0];
    const float* gamma = (const float*)d_in[1];
    const float* dist  = (const float*)d_in[2];
    const float* ln1w  = (const float*)d_in[3];
    const float* ln1b  = (const float*)d_in[4];
    const float* qkvw  = (const float*)d_in[5];
    const float* qkvb  = (const float*)d_in[6];
    const float* projw = (const float*)d_in[7];
    const float* projb = (const float*)d_in[8];
    const float* ln2w  = (const float*)d_in[9];
    const float* ln2b  = (const float*)d_in[10];
    const float* w1    = (const float*)d_in[11];
    const float* b1    = (const float*)d_in[12];
    const float* w2    = (const float*)d_in[13];
    const float* b2    = (const float*)d_in[14];
    float* out = (float*)d_out;
    char* ws = (char*)d_ws;
    u16* wqkvT  = (u16*)(ws + 0);
    u16* wprojT = (u16*)(ws + 6291456);
    u16* w1T    = (u16*)(ws + 8388608);
    u16* w2T    = (u16*)(ws + 16777216);
    u16* hb     = (u16*)(ws + 33554432);
    u16* qb     = (u16*)(ws + 41943040);
    u16* kb     = (u16*)(ws + 50331648);
    u16* vtb    = (u16*)(ws + 58720256);
    u16* aob    = (u16*)(ws + 67108864);
    u16* gb     = hb;    // mlp1 output [4096][4096] bf16 spans 33.5-67.1 MB
    u16* h2b    = aob;   // ln2 output reuses ao slot (dead after mlp1)
    // mlp2 split-K bf16 partials (8 MB each), in regions dead by mlp2:
    u16* mp0 = (u16*)(ws + 0);          // wqkvT+wprojT (dead after proj)
    u16* mp1 = (u16*)(ws + 8388608);    // w1T (dead after mlp1)
    u16* mp2 = (u16*)(ws + 25165824);   // old distb slot (unused)
    u16* mp3 = (u16*)(ws + 67108864);   // aob/h2b (dead after mlp1)

    dim3 blk(256);
    transpose_cast<<<dim3(3072 / 32, 1024 / 32), blk, 0, stream>>>(qkvw, wqkvT, 1024, 3072);
    transpose_cast<<<dim3(1024 / 32, 1024 / 32), blk, 0, stream>>>(projw, wprojT, 1024, 1024);
    transpose_cast<<<dim3(4096 / 32, 1024 / 32), blk, 0, stream>>>(w1, w1T, 1024, 4096);
    transpose_cast<<<dim3(1024 / 32, 4096 / 32), blk, 0, stream>>>(w2, w2T, 4096, 1024);
    ln_bf16<<<4096, blk, 0, stream>>>(x, ln1w, ln1b, hb);
    gemm256_8ph<0><<<dim3(12, 16), dim3(512), 0, stream>>>(hb, wqkvT, qkvb, 1024, 1024,
                                                           nullptr, qb, kb, vtb);
    attn_fwd<<<dim3(16, 32), dim3(512), 0, stream>>>(qb, kb, vtb, dist, gamma, aob);
    gemm_bf16<1, 64><<<dim3(16, 32), blk, 0, stream>>>(aob, wprojT, projb, 4096, 1024, 1024,
                                                       x, out);
    ln_bf16<<<4096, blk, 0, stream>>>(out, ln2w, ln2b, h2b);
    gemm256_8ph<2><<<dim3(16, 16), dim3(512), 0, stream>>>(h2b, w1T, b1, 1024, 1024,
                                                           gb, nullptr, nullptr, nullptr);
    gemm256_8ph<3><<<dim3(4, 16, 4), dim3(512), 0, stream>>>(gb, w2T, nullptr, 4096, 1024,
                                                             mp0, mp1, mp2, mp3);
    combine4<<<4096, blk, 0, stream>>>(mp0, mp1, mp2, mp3, b2, out);
}

// Round 12
// 258.939 us; speedup vs baseline: 1.1313x; 1.0125x over previous
//
#include <hip/hip_runtime.h>
#include <hip/hip_bf16.h>

// ZoomTransformerBlock: B=2, N=2048, D=1024, H=16, DH=64, DF=4096
// R12: attn K/V staging -> global_load_lds with pre-swizzled source (no reg
//      round-trip, no VALU LDS writes; one barrier/tile unchanged);
//      4 transpose_cast launches merged into 1 kernel.
//      Rest identical to R11 (262us: split-K mlp2 + combine, 8-phase qkv/mlp1).

#define SCALE_ 0.03125f   // D^-0.5 = 1/32
#define EPS_   1e-5f
#define LOG2E_ 1.4426950408889634f
#define SC2_   (SCALE_ * LOG2E_)

typedef unsigned short u16;
typedef __attribute__((ext_vector_type(8))) short short8;
typedef __attribute__((ext_vector_type(4))) float f32x4;
typedef __attribute__((ext_vector_type(4))) unsigned short u16x4;

__device__ inline float b2f(u16 u){ unsigned x = ((unsigned)u) << 16; float f; __builtin_memcpy(&f, &x, 4); return f; }
__device__ inline u16 f2b(float f){ __hip_bfloat16 h = __float2bfloat16(f); u16 u; __builtin_memcpy(&u, &h, 2); return u; }

// async global->LDS, 16B per lane; LDS dest = wave-uniform base + lane*16 (linear)
__device__ inline void glds16(const u16* g, u16* l) {
    __builtin_amdgcn_global_load_lds(
        (const __attribute__((address_space(1))) void*)g,
        (__attribute__((address_space(3))) void*)l, 16, 0, 0);
}

// pack 2 f32 -> 1 dword of 2 bf16 (lo = a, hi = b)
__device__ inline unsigned cvtpk(float a, float b) {
    unsigned r;
    asm("v_cvt_pk_bf16_f32 %0, %1, %2" : "=v"(r) : "v"(a), "v"(b));
    return r;
}

// ---------------- fused transpose+cast for all 4 weights: [K][N] f32 -> [N][K] bf16 ----
__global__ __launch_bounds__(256) void transpose_cast4(
    const float* __restrict__ s0, const float* __restrict__ s1,
    const float* __restrict__ s2, const float* __restrict__ s3,
    u16* __restrict__ d0, u16* __restrict__ d1,
    u16* __restrict__ d2, u16* __restrict__ d3) {
    __shared__ float t[32][33];
    int bid = blockIdx.x;
    const float* src; u16* dst; int K, N, nbx, base;
    if (bid < 3072)      { src = s0; dst = d0; K = 1024; N = 3072; nbx = 96;  base = 0; }
    else if (bid < 4096) { src = s1; dst = d1; K = 1024; N = 1024; nbx = 32;  base = 3072; }
    else if (bid < 8192) { src = s2; dst = d2; K = 1024; N = 4096; nbx = 128; base = 4096; }
    else                 { src = s3; dst = d3; K = 4096; N = 1024; nbx = 32;  base = 8192; }
    int lb = bid - base;
    int nb = (lb % nbx) * 32, kb = (lb / nbx) * 32;
    int tx = threadIdx.x & 31, ty = threadIdx.x >> 5;
    for (int i = 0; i < 4; i++) {
        int r = ty + i * 8;
        t[r][tx] = src[(size_t)(kb + r) * N + nb + tx];
    }
    __syncthreads();
    for (int i = 0; i < 4; i++) {
        int r = ty + i * 8;
        dst[(size_t)(nb + r) * K + kb + tx] = f2b(t[tx][r]);
    }
}

// ---------------- LayerNorm row (D=1024) f32 -> bf16 ----------------
__global__ __launch_bounds__(256) void ln_bf16(const float* __restrict__ x,
                                               const float* __restrict__ w,
                                               const float* __restrict__ b,
                                               u16* __restrict__ out) {
    int row = blockIdx.x, t = threadIdx.x;
    float4 v = ((const float4*)(x + (size_t)row * 1024))[t];
    float s1 = v.x + v.y + v.z + v.w;
    float s2 = v.x * v.x + v.y * v.y + v.z * v.z + v.w * v.w;
    for (int o = 32; o > 0; o >>= 1) { s1 += __shfl_xor(s1, o); s2 += __shfl_xor(s2, o); }
    __shared__ float a1[4], a2[4];
    if ((t & 63) == 0) { a1[t >> 6] = s1; a2[t >> 6] = s2; }
    __syncthreads();
    s1 = a1[0] + a1[1] + a1[2] + a1[3];
    s2 = a2[0] + a2[1] + a2[2] + a2[3];
    float mu = s1 * (1.0f / 1024.0f);
    float var = s2 * (1.0f / 1024.0f) - mu * mu;
    float rs = rsqrtf(var + EPS_);
    float4 wv = ((const float4*)w)[t];
    float4 bv = ((const float4*)b)[t];
    u16x4 o;
    o[0] = f2b((v.x - mu) * rs * wv.x + bv.x);
    o[1] = f2b((v.y - mu) * rs * wv.y + bv.y);
    o[2] = f2b((v.z - mu) * rs * wv.z + bv.z);
    o[3] = f2b((v.w - mu) * rs * wv.w + bv.w);
    ((u16x4*)(out + (size_t)row * 1024))[t] = o;
}

// ---------------- combine: out += b2f(p0..p3) + bias   (mlp2 split-K merge) ----------------
__global__ __launch_bounds__(256) void combine4(
    const u16* __restrict__ p0, const u16* __restrict__ p1,
    const u16* __restrict__ p2, const u16* __restrict__ p3,
    const float* __restrict__ bias, float* __restrict__ out) {
    size_t i = (size_t)(blockIdx.x * 256 + threadIdx.x) * 4;   // grid covers 4096*1024/4
    u16x4 a0 = *(const u16x4*)(p0 + i);
    u16x4 a1 = *(const u16x4*)(p1 + i);
    u16x4 a2 = *(const u16x4*)(p2 + i);
    u16x4 a3 = *(const u16x4*)(p3 + i);
    float4 ov = *(float4*)(out + i);
    float4 bv = *(const float4*)(bias + (i & 1023));
    ov.x += b2f(a0[0]) + b2f(a1[0]) + b2f(a2[0]) + b2f(a3[0]) + bv.x;
    ov.y += b2f(a0[1]) + b2f(a1[1]) + b2f(a2[1]) + b2f(a3[1]) + bv.y;
    ov.z += b2f(a0[2]) + b2f(a1[2]) + b2f(a2[2]) + b2f(a3[2]) + bv.z;
    ov.w += b2f(a0[3]) + b2f(a1[3]) + b2f(a2[3]) + b2f(a3[3]) + bv.w;
    *(float4*)(out + i) = ov;
}

// ======== 8-phase 256x256 MFMA GEMM, BK=32, 4-deep K-tile pipeline ========
// MODE 0: qkv scatter (+bias, q pre-scaled)   MODE 2: outb = gelu(acc+bias), ld 4096
// MODE 3: bf16 partial per K-split (z), ld 1024; buffers: outb,qp,kp,vtp = p0..p3
template <int MODE>
__global__ __launch_bounds__(512) void gemm256_8ph(
    const u16* __restrict__ A, const u16* __restrict__ Bt,
    const float* __restrict__ bias, int K, int ksl,
    u16* __restrict__ outb,
    u16* __restrict__ qp, u16* __restrict__ kp, u16* __restrict__ vtp) {
    __shared__ u16 LS[4][2][256 * 32];   // 128 KiB
    int tid = threadIdx.x;
    int w = tid >> 6, lane = tid & 63, g = lane >> 4, ln = lane & 15;
    int wr = w >> 2, wc = w & 3;
    int gx = gridDim.x;
    int nwg = gx * gridDim.y;
    int lin = blockIdx.y * gx + blockIdx.x;
    int swz = (lin & 7) * (nwg >> 3) + (lin >> 3);
    int bx = swz % gx, by = swz / gx;
    int br = by * 256, bc = bx * 256;
    int k0 = blockIdx.z * ksl;
    int jx = (((lane & 3) ^ ((lane >> 3) & 3)) << 3);
    const u16* Ast = A + (size_t)(br + w * 32 + (lane >> 2)) * K + k0 + jx;
    const u16* Bst = Bt + (size_t)(bc + w * 32 + (lane >> 2)) * K + k0 + jx;
    size_t r16 = (size_t)16 * K;
    const int ldsW = (w * 32) * 32;
    f32x4 acc[8][4] = {};
    int NT = ksl >> 5;
    int slotr = ((g ^ ((ln >> 1) & 3)) << 3);
    for (int kt = 0; kt < 3; ++kt) {
        glds16(Ast + (size_t)kt * 32, &LS[kt][0][ldsW]);
        glds16(Ast + (size_t)kt * 32 + r16, &LS[kt][0][ldsW + 512]);
        glds16(Bst + (size_t)kt * 32, &LS[kt][1][ldsW]);
        glds16(Bst + (size_t)kt * 32 + r16, &LS[kt][1][ldsW + 512]);
    }
    asm volatile("s_waitcnt vmcnt(8)" ::: "memory");
    __builtin_amdgcn_s_barrier();
    short8 aa[4], bb[4];
    for (int kt = 0; kt < NT; ++kt) {
        const u16* bufA = &LS[kt & 3][0][0];
        const u16* bufB = &LS[kt & 3][1][0];
        int s3 = kt + 3;
        #pragma unroll
        for (int m = 0; m < 4; ++m)
            aa[m] = *(const short8*)&bufA[(wr * 128 + m * 16 + ln) * 32 + slotr];
        #pragma unroll
        for (int n = 0; n < 4; ++n)
            bb[n] = *(const short8*)&bufB[(wc * 64 + n * 16 + ln) * 32 + slotr];
        if (s3 < NT) {
            u16* d = &LS[s3 & 3][0][ldsW];
            glds16(Ast + (size_t)s3 * 32, d);
            glds16(Ast + (size_t)s3 * 32 + r16, d + 512);
        }
        __builtin_amdgcn_s_barrier();
        asm volatile("s_waitcnt lgkmcnt(0)" ::: "memory");
        __builtin_amdgcn_sched_barrier(0);
        __builtin_amdgcn_s_setprio(1);
        #pragma unroll
        for (int m = 0; m < 4; ++m)
            #pragma unroll
            for (int n = 0; n < 4; ++n)
                acc[m][n] = __builtin_amdgcn_mfma_f32_16x16x32_bf16(aa[m], bb[n], acc[m][n], 0, 0, 0);
        __builtin_amdgcn_s_setprio(0);
        __builtin_amdgcn_sched_barrier(0);
        __builtin_amdgcn_s_barrier();
        #pragma unroll
        for (int m = 0; m < 4; ++m)
            aa[m] = *(const short8*)&bufA[(wr * 128 + 64 + m * 16 + ln) * 32 + slotr];
        if (s3 < NT) {
            u16* d = &LS[s3 & 3][1][ldsW];
            glds16(Bst + (size_t)s3 * 32, d);
            glds16(Bst + (size_t)s3 * 32 + r16, d + 512);
        }
        if (kt + 3 < NT)      asm volatile("s_waitcnt vmcnt(8)" ::: "memory");
        else if (kt + 2 < NT) asm volatile("s_waitcnt vmcnt(4)" ::: "memory");
        else if (kt + 1 < NT) asm volatile("s_waitcnt vmcnt(0)" ::: "memory");
        __builtin_amdgcn_s_barrier();
        asm volatile("s_waitcnt lgkmcnt(0)" ::: "memory");
        __builtin_amdgcn_sched_barrier(0);
        __builtin_amdgcn_s_setprio(1);
        #pragma unroll
        for (int m = 0; m < 4; ++m)
            #pragma unroll
            for (int n = 0; n < 4; ++n)
                acc[4 + m][n] = __builtin_amdgcn_mfma_f32_16x16x32_bf16(aa[m], bb[n], acc[4 + m][n], 0, 0, 0);
        __builtin_amdgcn_s_setprio(0);
        __builtin_amdgcn_sched_barrier(0);
        __builtin_amdgcn_s_barrier();
    }
    #pragma unroll
    for (int m = 0; m < 8; ++m) {
        int row0 = br + wr * 128 + m * 16 + g * 4;
        #pragma unroll
        for (int n = 0; n < 4; ++n) {
            int col = bc + wc * 64 + n * 16 + ln;
            if constexpr (MODE == 0) {
                float bv = bias[col];
                int which = col >> 10, cc = col & 1023, hh = cc >> 6, dh = cc & 63;
                int bb2 = row0 >> 11, nn0 = row0 & 2047;
                size_t bh = (size_t)(bb2 * 16 + hh);
                if (which == 0) {
                    for (int r = 0; r < 4; r++)
                        qp[((bh * 2048 + nn0 + r) << 6) + dh] = f2b((acc[m][n][r] + bv) * SC2_);
                } else if (which == 1) {
                    for (int r = 0; r < 4; r++)
                        kp[((bh * 2048 + nn0 + r) << 6) + dh] = f2b(acc[m][n][r] + bv);
                } else {
                    u16x4 o;
                    for (int r = 0; r < 4; r++) o[r] = f2b(acc[m][n][r] + bv);
                    *(u16x4*)&vtp[((bh * 64 + dh) << 11) + nn0] = o;
                }
            } else if constexpr (MODE == 2) {
                float bv = bias[col];
                for (int r = 0; r < 4; r++) {
                    float v = acc[m][n][r] + bv;
                    float gl = 0.5f * v * (1.0f + erff(v * 0.7071067811865476f));
                    outb[(size_t)(row0 + r) * 4096 + col] = f2b(gl);
                }
            } else {   // MODE 3: bf16 partial (no bias; combine adds it)
                u16* pb = (blockIdx.z == 0) ? outb : (blockIdx.z == 1) ? qp
                        : (blockIdx.z == 2) ? kp : vtp;
                for (int r = 0; r < 4; r++)
                    pb[(size_t)(row0 + r) * 1024 + col] = f2b(acc[m][n][r]);
            }
        }
    }
}

// ---------------- bf16 GEMM (R8 structure): MODE 1: out = res + acc + bias ----------------
template <int MODE, int BN>
__global__ __launch_bounds__(256) void gemm_bf16(
    const u16* __restrict__ A, const u16* __restrict__ Bt,
    const float* __restrict__ bias, int M, int N, int K,
    const float* __restrict__ res, float* __restrict__ outf) {
    constexpr int NN = BN / 32;
    __shared__ u16 As[128 * 64];
    __shared__ u16 Bs[BN * 64];
    int br = blockIdx.y * 128, bc = blockIdx.x * BN;
    int tid = threadIdx.x;
    int w = tid >> 6, lane = tid & 63, g = lane >> 4, ln = lane & 15;
    int wr = (w >> 1) * 64, wc = (w & 1) * (BN / 2);
    f32x4 acc[4][NN] = {};
    int sgcol = (((lane & 7) ^ (lane >> 3)) << 3);
    int arow = w * 32 + (lane >> 3);
    int brow = w * (BN / 4) + (lane >> 3);
    const u16* Ap = A + (size_t)(br + arow) * K + sgcol;
    const u16* Bp = Bt + (size_t)(bc + brow) * K + sgcol;
    u16* lA = &As[(w * 32) * 64];
    u16* lB = &Bs[(w * (BN / 4)) * 64];
    size_t rstep = (size_t)8 * K;
    for (int kt = 0; kt < K; kt += 64) {
        __syncthreads();
        #pragma unroll
        for (int i = 0; i < 4; i++) glds16(Ap + kt + i * rstep, lA + i * 512);
        #pragma unroll
        for (int i = 0; i < BN / 32; i++) glds16(Bp + kt + i * rstep, lB + i * 512);
        __syncthreads();
        #pragma unroll
        for (int kk = 0; kk < 2; kk++) {
            int so = (((kk << 2) + g) ^ (ln & 7)) << 3;
            short8 af[4], bfr[NN];
            #pragma unroll
            for (int m = 0; m < 4; m++)  af[m]  = *(const short8*)&As[(wr + m * 16 + ln) * 64 + so];
            #pragma unroll
            for (int n = 0; n < NN; n++) bfr[n] = *(const short8*)&Bs[(wc + n * 16 + ln) * 64 + so];
            #pragma unroll
            for (int m = 0; m < 4; m++)
                #pragma unroll
                for (int n = 0; n < NN; n++)
                    acc[m][n] = __builtin_amdgcn_mfma_f32_16x16x32_bf16(af[m], bfr[n], acc[m][n], 0, 0, 0);
        }
    }
    #pragma unroll
    for (int m = 0; m < 4; m++) {
        int row0 = br + wr + m * 16 + g * 4;
        #pragma unroll
        for (int n = 0; n < NN; n++) {
            int col = bc + wc + n * 16 + ln;
            float bv = bias[col];
            for (int r = 0; r < 4; r++) {
                size_t idx = (size_t)(row0 + r) * 1024 + col;
                outf[idx] = res[idx] + acc[m][n][r] + bv;
            }
        }
    }
}

// ---------------- flash attention: 8 waves (QBLK=128), glds16 K/V staging ----------------
// grid (16 q-tiles, 32 bh), 8 waves/wg; q pre-scaled by SCALE*LOG2E; dist raw f32.
// LDS slot s of row r holds global slot s^(r&7); wave w stages rows 8w..8w+7 of
// K and V^T each (one glds16 apiece) with pre-swizzled per-lane source.
__global__ __launch_bounds__(512) void attn_fwd(
    const u16* __restrict__ qg, const u16* __restrict__ kg, const u16* __restrict__ vtg,
    const float* __restrict__ dist, const float* __restrict__ gamma, u16* __restrict__ ao) {
    __shared__ u16 Ks[2][64 * 64];   // 16 KB
    __shared__ u16 Vs[2][64 * 64];   // 16 KB (V^T)
    __shared__ u16 Ps[8][16 * 64];   // 16 KB
    int qt = blockIdx.x, bh = blockIdx.y;
    int b = bh >> 4, h = bh & 15;
    int tid = threadIdx.x, w = tid >> 6, lane = tid & 63, g = lane >> 4, ln = lane & 15;
    float gam = gamma[bh] * LOG2E_;
    int qglob = qt * 128 + w * 16 + ln;
    const u16* qrow = qg + ((size_t)bh * 2048 + qglob) * 64;
    short8 qf0 = *(const short8*)(qrow + g * 8);
    short8 qf1 = *(const short8*)(qrow + 32 + g * 8);
    const float* dbase = dist + (size_t)qglob * 2048 + g * 4;
    float m2 = -3.0e38f, lsum = 0.0f;
    f32x4 acco[4] = {};
    // glds16 staging: wave w covers rows 8w..8w+7; lane -> row 8w+(lane>>3), slot lane&7
    int lrow = lane >> 3;
    int gsl = (((lane & 7) ^ (lrow & 7)) << 3);   // pre-swizzled source col (u16)
    const u16* kstg = kg + ((size_t)(bh * 2048 + w * 8 + lrow)) * 64 + gsl;
    const u16* vstg = vtg + ((size_t)(bh * 64 + w * 8 + lrow)) * 2048 + gsl;
    u16* lk[2] = { &Ks[0][(w * 8) * 64], &Ks[1][(w * 8) * 64] };
    u16* lv[2] = { &Vs[0][(w * 8) * 64], &Vs[1][(w * 8) * 64] };
    glds16(kstg, lk[0]);
    glds16(vstg, lv[0]);
    f32x4 dcv[4];
    #pragma unroll
    for (int nb = 0; nb < 4; nb++) dcv[nb] = *(const f32x4*)(dbase + nb * 16);
    __syncthreads();   // drains glds16 (vmcnt(0) before barrier)
    int cur = 0;
    int so0 = (g ^ (ln & 7)) << 3, so1 = ((4 + g) ^ (ln & 7)) << 3;
    for (int kt = 0; kt < 32; kt++) {
        // issue next tile's K/V into other buffer + dist into regs (issue-early)
        f32x4 dnx[4];
        if (kt < 31) {
            glds16(kstg + (size_t)(kt + 1) * 4096, lk[cur ^ 1]);
            glds16(vstg + (size_t)(kt + 1) * 64, lv[cur ^ 1]);
            #pragma unroll
            for (int nb = 0; nb < 4; nb++)
                dnx[nb] = *(const f32x4*)(dbase + (kt + 1) * 64 + nb * 16);
        }
        // S^T = K Q^T : sa[nb][r] = S[kv=nb*16+g*4+r][q=ln]
        f32x4 sa[4] = {};
        __builtin_amdgcn_s_setprio(1);
        #pragma unroll
        for (int nb = 0; nb < 4; nb++) {
            short8 kf0 = *(const short8*)&Ks[cur][(nb * 16 + ln) * 64 + so0];
            short8 kf1 = *(const short8*)&Ks[cur][(nb * 16 + ln) * 64 + so1];
            sa[nb] = __builtin_amdgcn_mfma_f32_16x16x32_bf16(kf0, qf0, sa[nb], 0, 0, 0);
            sa[nb] = __builtin_amdgcn_mfma_f32_16x16x32_bf16(kf1, qf1, sa[nb], 0, 0, 0);
        }
        __builtin_amdgcn_s_setprio(0);
        // softmax in log2 domain (SCALE*LOG2E folded into q; LOG2E in gam)
        float sv[4][4], pm = -3.0e38f;
        #pragma unroll
        for (int nb = 0; nb < 4; nb++) {
            #pragma unroll
            for (int r = 0; r < 4; r++)
                sv[nb][r] = sa[nb][r] - gam * dcv[nb][r];
            pm = fmaxf(pm, fmaxf(fmaxf(sv[nb][0], sv[nb][1]), fmaxf(sv[nb][2], sv[nb][3])));
        }
        pm = fmaxf(pm, __shfl_xor(pm, 16));
        pm = fmaxf(pm, __shfl_xor(pm, 32));
        if (!__all(pm - m2 <= 8.0f)) {   // defer-max: rescale only on real growth
            float nm = fmaxf(m2, pm);
            float al = __builtin_exp2f(m2 - nm);
            m2 = nm;
            lsum *= al;
            #pragma unroll
            for (int db = 0; db < 4; db++) acco[db] *= al;
        }
        float ps = 0.0f;
        #pragma unroll
        for (int nb = 0; nb < 4; nb++) {
            float e0 = __builtin_exp2f(sv[nb][0] - m2);
            float e1 = __builtin_exp2f(sv[nb][1] - m2);
            float e2 = __builtin_exp2f(sv[nb][2] - m2);
            float e3 = __builtin_exp2f(sv[nb][3] - m2);
            ps += (e0 + e1) + (e2 + e3);
            union { unsigned u[2]; u16x4 v; } pk;
            pk.u[0] = cvtpk(e0, e1);
            pk.u[1] = cvtpk(e2, e3);
            int off = nb * 16 + g * 4;
            *(u16x4*)&Ps[w][ln * 64 + (((off >> 3) ^ (ln & 7)) << 3) + (off & 7)] = pk.v;
        }
        ps += __shfl_xor(ps, 16);
        ps += __shfl_xor(ps, 32);
        lsum += ps;
        // PV^T: out^T[d][q] += V^T[d][kv] P^T[kv][q]
        short8 pf0 = *(const short8*)&Ps[w][ln * 64 + so0];
        short8 pf1 = *(const short8*)&Ps[w][ln * 64 + so1];
        __builtin_amdgcn_s_setprio(1);
        #pragma unroll
        for (int db = 0; db < 4; db++) {
            short8 vf0 = *(const short8*)&Vs[cur][(db * 16 + ln) * 64 + so0];
            short8 vf1 = *(const short8*)&Vs[cur][(db * 16 + ln) * 64 + so1];
            acco[db] = __builtin_amdgcn_mfma_f32_16x16x32_bf16(vf0, pf0, acco[db], 0, 0, 0);
            acco[db] = __builtin_amdgcn_mfma_f32_16x16x32_bf16(vf1, pf1, acco[db], 0, 0, 0);
        }
        __builtin_amdgcn_s_setprio(0);
        if (kt < 31) {
            #pragma unroll
            for (int nb = 0; nb < 4; nb++) dcv[nb] = dnx[nb];
        }
        __syncthreads();   // drains glds16 of next tile + all LDS reads
        cur ^= 1;
    }
    float inv = 1.0f / lsum;
    u16* aop = ao + (size_t)(b * 2048 + qglob) * 1024 + h * 64 + g * 4;
    #pragma unroll
    for (int db = 0; db < 4; db++) {
        u16x4 o;
        #pragma unroll
        for (int r = 0; r < 4; r++) o[r] = f2b(acco[db][r] * inv);
        *(u16x4*)(aop + db * 16) = o;
    }
}

extern "C" void kernel_launch(void* const* d_in, const int* in_sizes, int n_in,
                              void* d_out, int out_size, void* d_ws, size_t ws_size,
                              hipStream_t stream) {
    const float* x     = (const float*)d_in[0];
    const float* gamma = (const float*)d_in[1];
    const float* dist  = (const float*)d_in[2];
    const float* ln1w  = (const float*)d_in[3];
    const float* ln1b  = (const float*)d_in[4];
    const float* qkvw  = (const float*)d_in[5];
    const float* qkvb  = (const float*)d_in[6];
    const float* projw = (const float*)d_in[7];
    const float* projb = (const float*)d_in[8];
    const float* ln2w  = (const float*)d_in[9];
    const float* ln2b  = (const float*)d_in[10];
    const float* w1    = (const float*)d_in[11];
    const float* b1    = (const float*)d_in[12];
    const float* w2    = (const float*)d_in[13];
    const float* b2    = (const float*)d_in[14];
    float* out = (float*)d_out;
    char* ws = (char*)d_ws;
    u16* wqkvT  = (u16*)(ws + 0);
    u16* wprojT = (u16*)(ws + 6291456);
    u16* w1T    = (u16*)(ws + 8388608);
    u16* w2T    = (u16*)(ws + 16777216);
    u16* hb     = (u16*)(ws + 33554432);
    u16* qb     = (u16*)(ws + 41943040);
    u16* kb     = (u16*)(ws + 50331648);
    u16* vtb    = (u16*)(ws + 58720256);
    u16* aob    = (u16*)(ws + 67108864);
    u16* gb     = hb;    // mlp1 output [4096][4096] bf16 spans 33.5-67.1 MB
    u16* h2b    = aob;   // ln2 output reuses ao slot (dead after mlp1)
    // mlp2 split-K bf16 partials (8 MB each), in regions dead by mlp2:
    u16* mp0 = (u16*)(ws + 0);          // wqkvT+wprojT (dead after proj)
    u16* mp1 = (u16*)(ws + 8388608);    // w1T (dead after mlp1)
    u16* mp2 = (u16*)(ws + 25165824);   // unused region
    u16* mp3 = (u16*)(ws + 67108864);   // aob/h2b (dead after mlp1)

    dim3 blk(256);
    transpose_cast4<<<12288, blk, 0, stream>>>(qkvw, projw, w1, w2,
                                               wqkvT, wprojT, w1T, w2T);
    ln_bf16<<<4096, blk, 0, stream>>>(x, ln1w, ln1b, hb);
    gemm256_8ph<0><<<dim3(12, 16), dim3(512), 0, stream>>>(hb, wqkvT, qkvb, 1024, 1024,
                                                           nullptr, qb, kb, vtb);
    attn_fwd<<<dim3(16, 32), dim3(512), 0, stream>>>(qb, kb, vtb, dist, gamma, aob);
    gemm_bf16<1, 64><<<dim3(16, 32), blk, 0, stream>>>(aob, wprojT, projb, 4096, 1024, 1024,
                                                       x, out);
    ln_bf16<<<4096, blk, 0, stream>>>(out, ln2w, ln2b, h2b);
    gemm256_8ph<2><<<dim3(16, 16), dim3(512), 0, stream>>>(h2b, w1T, b1, 1024, 1024,
                                                           gb, nullptr, nullptr, nullptr);
    gemm256_8ph<3><<<dim3(4, 16, 4), dim3(512), 0, stream>>>(gb, w2T, nullptr, 4096, 1024,
                                                             mp0, mp1, mp2, mp3);
    combine4<<<4096, blk, 0, stream>>>(mp0, mp1, mp2, mp3, b2, out);
}

// Round 13
// 254.032 us; speedup vs baseline: 1.1531x; 1.0193x over previous
//
#include <hip/hip_runtime.h>
#include <hip/hip_bf16.h>

// ZoomTransformerBlock: B=2, N=2048, D=1024, H=16, DH=64, DF=4096
// R13: attn -> R11 reg-staged write-late staging (measured best) + per-lane
//      partial lsum (cross-lane sum hoisted out of the loop);
//      transpose_cast4 + LN1 merged into one prep kernel (-1 launch).
//      Rest identical to R12 (split-K mlp2 + combine, 8-phase qkv/mlp1).

#define SCALE_ 0.03125f   // D^-0.5 = 1/32
#define EPS_   1e-5f
#define LOG2E_ 1.4426950408889634f
#define SC2_   (SCALE_ * LOG2E_)

typedef unsigned short u16;
typedef __attribute__((ext_vector_type(8))) short short8;
typedef __attribute__((ext_vector_type(4))) float f32x4;
typedef __attribute__((ext_vector_type(4))) unsigned short u16x4;

__device__ inline float b2f(u16 u){ unsigned x = ((unsigned)u) << 16; float f; __builtin_memcpy(&f, &x, 4); return f; }
__device__ inline u16 f2b(float f){ __hip_bfloat16 h = __float2bfloat16(f); u16 u; __builtin_memcpy(&u, &h, 2); return u; }

// async global->LDS, 16B per lane; LDS dest = wave-uniform base + lane*16 (linear)
__device__ inline void glds16(const u16* g, u16* l) {
    __builtin_amdgcn_global_load_lds(
        (const __attribute__((address_space(1))) void*)g,
        (__attribute__((address_space(3))) void*)l, 16, 0, 0);
}

// pack 2 f32 -> 1 dword of 2 bf16 (lo = a, hi = b)
__device__ inline unsigned cvtpk(float a, float b) {
    unsigned r;
    asm("v_cvt_pk_bf16_f32 %0, %1, %2" : "=v"(r) : "v"(a), "v"(b));
    return r;
}

// ---------------- fused prep: 4x transpose+cast (blocks 0..12287) + LN1 (12288..16383) ----
__global__ __launch_bounds__(256) void prep_fused(
    const float* __restrict__ s0, const float* __restrict__ s1,
    const float* __restrict__ s2, const float* __restrict__ s3,
    u16* __restrict__ d0, u16* __restrict__ d1,
    u16* __restrict__ d2, u16* __restrict__ d3,
    const float* __restrict__ x, const float* __restrict__ lw,
    const float* __restrict__ lb, u16* __restrict__ ho) {
    int bid = blockIdx.x;
    if (bid < 12288) {
        __shared__ float t[32][33];
        const float* src; u16* dst; int K, N, nbx, base;
        if (bid < 3072)      { src = s0; dst = d0; K = 1024; N = 3072; nbx = 96;  base = 0; }
        else if (bid < 4096) { src = s1; dst = d1; K = 1024; N = 1024; nbx = 32;  base = 3072; }
        else if (bid < 8192) { src = s2; dst = d2; K = 1024; N = 4096; nbx = 128; base = 4096; }
        else                 { src = s3; dst = d3; K = 4096; N = 1024; nbx = 32;  base = 8192; }
        int lb2 = bid - base;
        int nb = (lb2 % nbx) * 32, kb = (lb2 / nbx) * 32;
        int tx = threadIdx.x & 31, ty = threadIdx.x >> 5;
        for (int i = 0; i < 4; i++) {
            int r = ty + i * 8;
            t[r][tx] = src[(size_t)(kb + r) * N + nb + tx];
        }
        __syncthreads();
        for (int i = 0; i < 4; i++) {
            int r = ty + i * 8;
            dst[(size_t)(nb + r) * K + kb + tx] = f2b(t[tx][r]);
        }
    } else {
        int row = bid - 12288, t = threadIdx.x;
        float4 v = ((const float4*)(x + (size_t)row * 1024))[t];
        float s1v = v.x + v.y + v.z + v.w;
        float s2v = v.x * v.x + v.y * v.y + v.z * v.z + v.w * v.w;
        for (int o = 32; o > 0; o >>= 1) { s1v += __shfl_xor(s1v, o); s2v += __shfl_xor(s2v, o); }
        __shared__ float a1[4], a2[4];
        if ((t & 63) == 0) { a1[t >> 6] = s1v; a2[t >> 6] = s2v; }
        __syncthreads();
        s1v = a1[0] + a1[1] + a1[2] + a1[3];
        s2v = a2[0] + a2[1] + a2[2] + a2[3];
        float mu = s1v * (1.0f / 1024.0f);
        float var = s2v * (1.0f / 1024.0f) - mu * mu;
        float rs = rsqrtf(var + EPS_);
        float4 wv = ((const float4*)lw)[t];
        float4 bv = ((const float4*)lb)[t];
        u16x4 o;
        o[0] = f2b((v.x - mu) * rs * wv.x + bv.x);
        o[1] = f2b((v.y - mu) * rs * wv.y + bv.y);
        o[2] = f2b((v.z - mu) * rs * wv.z + bv.z);
        o[3] = f2b((v.w - mu) * rs * wv.w + bv.w);
        ((u16x4*)(ho + (size_t)row * 1024))[t] = o;
    }
}

// ---------------- LayerNorm row (D=1024) f32 -> bf16 (LN2) ----------------
__global__ __launch_bounds__(256) void ln_bf16(const float* __restrict__ x,
                                               const float* __restrict__ w,
                                               const float* __restrict__ b,
                                               u16* __restrict__ out) {
    int row = blockIdx.x, t = threadIdx.x;
    float4 v = ((const float4*)(x + (size_t)row * 1024))[t];
    float s1 = v.x + v.y + v.z + v.w;
    float s2 = v.x * v.x + v.y * v.y + v.z * v.z + v.w * v.w;
    for (int o = 32; o > 0; o >>= 1) { s1 += __shfl_xor(s1, o); s2 += __shfl_xor(s2, o); }
    __shared__ float a1[4], a2[4];
    if ((t & 63) == 0) { a1[t >> 6] = s1; a2[t >> 6] = s2; }
    __syncthreads();
    s1 = a1[0] + a1[1] + a1[2] + a1[3];
    s2 = a2[0] + a2[1] + a2[2] + a2[3];
    float mu = s1 * (1.0f / 1024.0f);
    float var = s2 * (1.0f / 1024.0f) - mu * mu;
    float rs = rsqrtf(var + EPS_);
    float4 wv = ((const float4*)w)[t];
    float4 bv = ((const float4*)b)[t];
    u16x4 o;
    o[0] = f2b((v.x - mu) * rs * wv.x + bv.x);
    o[1] = f2b((v.y - mu) * rs * wv.y + bv.y);
    o[2] = f2b((v.z - mu) * rs * wv.z + bv.z);
    o[3] = f2b((v.w - mu) * rs * wv.w + bv.w);
    ((u16x4*)(out + (size_t)row * 1024))[t] = o;
}

// ---------------- combine: out += b2f(p0..p3) + bias   (mlp2 split-K merge) ----------------
__global__ __launch_bounds__(256) void combine4(
    const u16* __restrict__ p0, const u16* __restrict__ p1,
    const u16* __restrict__ p2, const u16* __restrict__ p3,
    const float* __restrict__ bias, float* __restrict__ out) {
    size_t i = (size_t)(blockIdx.x * 256 + threadIdx.x) * 4;   // grid covers 4096*1024/4
    u16x4 a0 = *(const u16x4*)(p0 + i);
    u16x4 a1 = *(const u16x4*)(p1 + i);
    u16x4 a2 = *(const u16x4*)(p2 + i);
    u16x4 a3 = *(const u16x4*)(p3 + i);
    float4 ov = *(float4*)(out + i);
    float4 bv = *(const float4*)(bias + (i & 1023));
    ov.x += b2f(a0[0]) + b2f(a1[0]) + b2f(a2[0]) + b2f(a3[0]) + bv.x;
    ov.y += b2f(a0[1]) + b2f(a1[1]) + b2f(a2[1]) + b2f(a3[1]) + bv.y;
    ov.z += b2f(a0[2]) + b2f(a1[2]) + b2f(a2[2]) + b2f(a3[2]) + bv.z;
    ov.w += b2f(a0[3]) + b2f(a1[3]) + b2f(a2[3]) + b2f(a3[3]) + bv.w;
    *(float4*)(out + i) = ov;
}

// ======== 8-phase 256x256 MFMA GEMM, BK=32, 4-deep K-tile pipeline ========
// MODE 0: qkv scatter (+bias, q pre-scaled)   MODE 2: outb = gelu(acc+bias), ld 4096
// MODE 3: bf16 partial per K-split (z), ld 1024; buffers: outb,qp,kp,vtp = p0..p3
template <int MODE>
__global__ __launch_bounds__(512) void gemm256_8ph(
    const u16* __restrict__ A, const u16* __restrict__ Bt,
    const float* __restrict__ bias, int K, int ksl,
    u16* __restrict__ outb,
    u16* __restrict__ qp, u16* __restrict__ kp, u16* __restrict__ vtp) {
    __shared__ u16 LS[4][2][256 * 32];   // 128 KiB
    int tid = threadIdx.x;
    int w = tid >> 6, lane = tid & 63, g = lane >> 4, ln = lane & 15;
    int wr = w >> 2, wc = w & 3;
    int gx = gridDim.x;
    int nwg = gx * gridDim.y;
    int lin = blockIdx.y * gx + blockIdx.x;
    int swz = (lin & 7) * (nwg >> 3) + (lin >> 3);
    int bx = swz % gx, by = swz / gx;
    int br = by * 256, bc = bx * 256;
    int k0 = blockIdx.z * ksl;
    int jx = (((lane & 3) ^ ((lane >> 3) & 3)) << 3);
    const u16* Ast = A + (size_t)(br + w * 32 + (lane >> 2)) * K + k0 + jx;
    const u16* Bst = Bt + (size_t)(bc + w * 32 + (lane >> 2)) * K + k0 + jx;
    size_t r16 = (size_t)16 * K;
    const int ldsW = (w * 32) * 32;
    f32x4 acc[8][4] = {};
    int NT = ksl >> 5;
    int slotr = ((g ^ ((ln >> 1) & 3)) << 3);
    for (int kt = 0; kt < 3; ++kt) {
        glds16(Ast + (size_t)kt * 32, &LS[kt][0][ldsW]);
        glds16(Ast + (size_t)kt * 32 + r16, &LS[kt][0][ldsW + 512]);
        glds16(Bst + (size_t)kt * 32, &LS[kt][1][ldsW]);
        glds16(Bst + (size_t)kt * 32 + r16, &LS[kt][1][ldsW + 512]);
    }
    asm volatile("s_waitcnt vmcnt(8)" ::: "memory");
    __builtin_amdgcn_s_barrier();
    short8 aa[4], bb[4];
    for (int kt = 0; kt < NT; ++kt) {
        const u16* bufA = &LS[kt & 3][0][0];
        const u16* bufB = &LS[kt & 3][1][0];
        int s3 = kt + 3;
        #pragma unroll
        for (int m = 0; m < 4; ++m)
            aa[m] = *(const short8*)&bufA[(wr * 128 + m * 16 + ln) * 32 + slotr];
        #pragma unroll
        for (int n = 0; n < 4; ++n)
            bb[n] = *(const short8*)&bufB[(wc * 64 + n * 16 + ln) * 32 + slotr];
        if (s3 < NT) {
            u16* d = &LS[s3 & 3][0][ldsW];
            glds16(Ast + (size_t)s3 * 32, d);
            glds16(Ast + (size_t)s3 * 32 + r16, d + 512);
        }
        __builtin_amdgcn_s_barrier();
        asm volatile("s_waitcnt lgkmcnt(0)" ::: "memory");
        __builtin_amdgcn_sched_barrier(0);
        __builtin_amdgcn_s_setprio(1);
        #pragma unroll
        for (int m = 0; m < 4; ++m)
            #pragma unroll
            for (int n = 0; n < 4; ++n)
                acc[m][n] = __builtin_amdgcn_mfma_f32_16x16x32_bf16(aa[m], bb[n], acc[m][n], 0, 0, 0);
        __builtin_amdgcn_s_setprio(0);
        __builtin_amdgcn_sched_barrier(0);
        __builtin_amdgcn_s_barrier();
        #pragma unroll
        for (int m = 0; m < 4; ++m)
            aa[m] = *(const short8*)&bufA[(wr * 128 + 64 + m * 16 + ln) * 32 + slotr];
        if (s3 < NT) {
            u16* d = &LS[s3 & 3][1][ldsW];
            glds16(Bst + (size_t)s3 * 32, d);
            glds16(Bst + (size_t)s3 * 32 + r16, d + 512);
        }
        if (kt + 3 < NT)      asm volatile("s_waitcnt vmcnt(8)" ::: "memory");
        else if (kt + 2 < NT) asm volatile("s_waitcnt vmcnt(4)" ::: "memory");
        else if (kt + 1 < NT) asm volatile("s_waitcnt vmcnt(0)" ::: "memory");
        __builtin_amdgcn_s_barrier();
        asm volatile("s_waitcnt lgkmcnt(0)" ::: "memory");
        __builtin_amdgcn_sched_barrier(0);
        __builtin_amdgcn_s_setprio(1);
        #pragma unroll
        for (int m = 0; m < 4; ++m)
            #pragma unroll
            for (int n = 0; n < 4; ++n)
                acc[4 + m][n] = __builtin_amdgcn_mfma_f32_16x16x32_bf16(aa[m], bb[n], acc[4 + m][n], 0, 0, 0);
        __builtin_amdgcn_s_setprio(0);
        __builtin_amdgcn_sched_barrier(0);
        __builtin_amdgcn_s_barrier();
    }
    #pragma unroll
    for (int m = 0; m < 8; ++m) {
        int row0 = br + wr * 128 + m * 16 + g * 4;
        #pragma unroll
        for (int n = 0; n < 4; ++n) {
            int col = bc + wc * 64 + n * 16 + ln;
            if constexpr (MODE == 0) {
                float bv = bias[col];
                int which = col >> 10, cc = col & 1023, hh = cc >> 6, dh = cc & 63;
                int bb2 = row0 >> 11, nn0 = row0 & 2047;
                size_t bh = (size_t)(bb2 * 16 + hh);
                if (which == 0) {
                    for (int r = 0; r < 4; r++)
                        qp[((bh * 2048 + nn0 + r) << 6) + dh] = f2b((acc[m][n][r] + bv) * SC2_);
                } else if (which == 1) {
                    for (int r = 0; r < 4; r++)
                        kp[((bh * 2048 + nn0 + r) << 6) + dh] = f2b(acc[m][n][r] + bv);
                } else {
                    u16x4 o;
                    for (int r = 0; r < 4; r++) o[r] = f2b(acc[m][n][r] + bv);
                    *(u16x4*)&vtp[((bh * 64 + dh) << 11) + nn0] = o;
                }
            } else if constexpr (MODE == 2) {
                float bv = bias[col];
                for (int r = 0; r < 4; r++) {
                    float v = acc[m][n][r] + bv;
                    float gl = 0.5f * v * (1.0f + erff(v * 0.7071067811865476f));
                    outb[(size_t)(row0 + r) * 4096 + col] = f2b(gl);
                }
            } else {   // MODE 3: bf16 partial (no bias; combine adds it)
                u16* pb = (blockIdx.z == 0) ? outb : (blockIdx.z == 1) ? qp
                        : (blockIdx.z == 2) ? kp : vtp;
                for (int r = 0; r < 4; r++)
                    pb[(size_t)(row0 + r) * 1024 + col] = f2b(acc[m][n][r]);
            }
        }
    }
}

// ---------------- bf16 GEMM (R8 structure): MODE 1: out = res + acc + bias ----------------
template <int MODE, int BN>
__global__ __launch_bounds__(256) void gemm_bf16(
    const u16* __restrict__ A, const u16* __restrict__ Bt,
    const float* __restrict__ bias, int M, int N, int K,
    const float* __restrict__ res, float* __restrict__ outf) {
    constexpr int NN = BN / 32;
    __shared__ u16 As[128 * 64];
    __shared__ u16 Bs[BN * 64];
    int br = blockIdx.y * 128, bc = blockIdx.x * BN;
    int tid = threadIdx.x;
    int w = tid >> 6, lane = tid & 63, g = lane >> 4, ln = lane & 15;
    int wr = (w >> 1) * 64, wc = (w & 1) * (BN / 2);
    f32x4 acc[4][NN] = {};
    int sgcol = (((lane & 7) ^ (lane >> 3)) << 3);
    int arow = w * 32 + (lane >> 3);
    int brow = w * (BN / 4) + (lane >> 3);
    const u16* Ap = A + (size_t)(br + arow) * K + sgcol;
    const u16* Bp = Bt + (size_t)(bc + brow) * K + sgcol;
    u16* lA = &As[(w * 32) * 64];
    u16* lB = &Bs[(w * (BN / 4)) * 64];
    size_t rstep = (size_t)8 * K;
    for (int kt = 0; kt < K; kt += 64) {
        __syncthreads();
        #pragma unroll
        for (int i = 0; i < 4; i++) glds16(Ap + kt + i * rstep, lA + i * 512);
        #pragma unroll
        for (int i = 0; i < BN / 32; i++) glds16(Bp + kt + i * rstep, lB + i * 512);
        __syncthreads();
        #pragma unroll
        for (int kk = 0; kk < 2; kk++) {
            int so = (((kk << 2) + g) ^ (ln & 7)) << 3;
            short8 af[4], bfr[NN];
            #pragma unroll
            for (int m = 0; m < 4; m++)  af[m]  = *(const short8*)&As[(wr + m * 16 + ln) * 64 + so];
            #pragma unroll
            for (int n = 0; n < NN; n++) bfr[n] = *(const short8*)&Bs[(wc + n * 16 + ln) * 64 + so];
            #pragma unroll
            for (int m = 0; m < 4; m++)
                #pragma unroll
                for (int n = 0; n < NN; n++)
                    acc[m][n] = __builtin_amdgcn_mfma_f32_16x16x32_bf16(af[m], bfr[n], acc[m][n], 0, 0, 0);
        }
    }
    #pragma unroll
    for (int m = 0; m < 4; m++) {
        int row0 = br + wr + m * 16 + g * 4;
        #pragma unroll
        for (int n = 0; n < NN; n++) {
            int col = bc + wc + n * 16 + ln;
            float bv = bias[col];
            for (int r = 0; r < 4; r++) {
                size_t idx = (size_t)(row0 + r) * 1024 + col;
                outf[idx] = res[idx] + acc[m][n][r] + bv;
            }
        }
    }
}

// ---------------- flash attention: 8 waves (QBLK=128), reg-staged dbuf, per-lane lsum ----
// grid (16 q-tiles, 32 bh), 8 waves/wg; q pre-scaled by SCALE*LOG2E; dist raw f32.
__global__ __launch_bounds__(512) void attn_fwd(
    const u16* __restrict__ qg, const u16* __restrict__ kg, const u16* __restrict__ vtg,
    const float* __restrict__ dist, const float* __restrict__ gamma, u16* __restrict__ ao) {
    __shared__ u16 Ks[2][64 * 64];   // 16 KB
    __shared__ u16 Vs[2][64 * 64];   // 16 KB (V^T)
    __shared__ u16 Ps[8][16 * 64];   // 16 KB
    int qt = blockIdx.x, bh = blockIdx.y;
    int b = bh >> 4, h = bh & 15;
    int tid = threadIdx.x, w = tid >> 6, lane = tid & 63, g = lane >> 4, ln = lane & 15;
    float gam = gamma[bh] * LOG2E_;
    int qglob = qt * 128 + w * 16 + ln;
    const u16* qrow = qg + ((size_t)bh * 2048 + qglob) * 64;
    short8 qf0 = *(const short8*)(qrow + g * 8);
    short8 qf1 = *(const short8*)(qrow + 32 + g * 8);
    const float* dbase = dist + (size_t)qglob * 2048 + g * 4;
    float m2 = -3.0e38f, lsum = 0.0f;
    f32x4 acco[4] = {};
    // staging: 512 thr cover 64 rows x 8 x 16B for K and V^T; swizzled LDS write
    int srow = tid >> 3, seg = tid & 7;
    int ss = ((seg ^ (srow & 7)) << 3);
    const u16* kgp = kg + ((size_t)bh * 2048 + srow) * 64 + seg * 8;
    const u16* vgp = vtg + ((size_t)bh * 64 + srow) * 2048 + seg * 8;
    {   // prologue: tile 0
        short8 a0 = *(const short8*)(kgp);
        short8 c0 = *(const short8*)(vgp);
        *(short8*)&Ks[0][srow * 64 + ss] = a0;
        *(short8*)&Vs[0][srow * 64 + ss] = c0;
    }
    f32x4 dcv[4];
    #pragma unroll
    for (int nb = 0; nb < 4; nb++) dcv[nb] = *(const f32x4*)(dbase + nb * 16);
    __syncthreads();
    int cur = 0;
    int so0 = (g ^ (ln & 7)) << 3, so1 = ((4 + g) ^ (ln & 7)) << 3;
    for (int kt = 0; kt < 32; kt++) {
        // async-STAGE split: issue next tile's global loads NOW, consume after PV
        short8 kr0, vr0;
        f32x4 dnx[4];
        if (kt < 31) {
            kr0 = *(const short8*)(kgp + (kt + 1) * 4096);
            vr0 = *(const short8*)(vgp + (kt + 1) * 64);
            #pragma unroll
            for (int nb = 0; nb < 4; nb++)
                dnx[nb] = *(const f32x4*)(dbase + (kt + 1) * 64 + nb * 16);
        }
        // S^T = K Q^T : sa[nb][r] = S[kv=nb*16+g*4+r][q=ln]
        f32x4 sa[4] = {};
        __builtin_amdgcn_s_setprio(1);
        #pragma unroll
        for (int nb = 0; nb < 4; nb++) {
            short8 kf0 = *(const short8*)&Ks[cur][(nb * 16 + ln) * 64 + so0];
            short8 kf1 = *(const short8*)&Ks[cur][(nb * 16 + ln) * 64 + so1];
            sa[nb] = __builtin_amdgcn_mfma_f32_16x16x32_bf16(kf0, qf0, sa[nb], 0, 0, 0);
            sa[nb] = __builtin_amdgcn_mfma_f32_16x16x32_bf16(kf1, qf1, sa[nb], 0, 0, 0);
        }
        __builtin_amdgcn_s_setprio(0);
        // softmax in log2 domain (SCALE*LOG2E folded into q; LOG2E in gam)
        float sv[4][4], pm = -3.0e38f;
        #pragma unroll
        for (int nb = 0; nb < 4; nb++) {
            #pragma unroll
            for (int r = 0; r < 4; r++)
                sv[nb][r] = sa[nb][r] - gam * dcv[nb][r];
            pm = fmaxf(pm, fmaxf(fmaxf(sv[nb][0], sv[nb][1]), fmaxf(sv[nb][2], sv[nb][3])));
        }
        pm = fmaxf(pm, __shfl_xor(pm, 16));
        pm = fmaxf(pm, __shfl_xor(pm, 32));
        if (!__all(pm - m2 <= 8.0f)) {   // defer-max: rescale only on real growth
            float nm = fmaxf(m2, pm);
            float al = __builtin_exp2f(m2 - nm);
            m2 = nm;
            lsum *= al;
            #pragma unroll
            for (int db = 0; db < 4; db++) acco[db] *= al;
        }
        // per-lane partial sum; cross-lane reduction hoisted to after the loop
        #pragma unroll
        for (int nb = 0; nb < 4; nb++) {
            float e0 = __builtin_exp2f(sv[nb][0] - m2);
            float e1 = __builtin_exp2f(sv[nb][1] - m2);
            float e2 = __builtin_exp2f(sv[nb][2] - m2);
            float e3 = __builtin_exp2f(sv[nb][3] - m2);
            lsum += (e0 + e1) + (e2 + e3);
            union { unsigned u[2]; u16x4 v; } pk;
            pk.u[0] = cvtpk(e0, e1);
            pk.u[1] = cvtpk(e2, e3);
            int off = nb * 16 + g * 4;
            *(u16x4*)&Ps[w][ln * 64 + (((off >> 3) ^ (ln & 7)) << 3) + (off & 7)] = pk.v;
        }
        // PV^T: out^T[d][q] += V^T[d][kv] P^T[kv][q]
        short8 pf0 = *(const short8*)&Ps[w][ln * 64 + so0];
        short8 pf1 = *(const short8*)&Ps[w][ln * 64 + so1];
        __builtin_amdgcn_s_setprio(1);
        #pragma unroll
        for (int db = 0; db < 4; db++) {
            short8 vf0 = *(const short8*)&Vs[cur][(db * 16 + ln) * 64 + so0];
            short8 vf1 = *(const short8*)&Vs[cur][(db * 16 + ln) * 64 + so1];
            acco[db] = __builtin_amdgcn_mfma_f32_16x16x32_bf16(vf0, pf0, acco[db], 0, 0, 0);
            acco[db] = __builtin_amdgcn_mfma_f32_16x16x32_bf16(vf1, pf1, acco[db], 0, 0, 0);
        }
        __builtin_amdgcn_s_setprio(0);
        if (kt < 31) {   // write-late: regs -> other buffer, ONE barrier/tile
            int nx = cur ^ 1;
            *(short8*)&Ks[nx][srow * 64 + ss] = kr0;
            *(short8*)&Vs[nx][srow * 64 + ss] = vr0;
            #pragma unroll
            for (int nb = 0; nb < 4; nb++) dcv[nb] = dnx[nb];
            __syncthreads();
            cur = nx;
        }
    }
    lsum += __shfl_xor(lsum, 16);
    lsum += __shfl_xor(lsum, 32);
    float inv = 1.0f / lsum;
    u16* aop = ao + (size_t)(b * 2048 + qglob) * 1024 + h * 64 + g * 4;
    #pragma unroll
    for (int db = 0; db < 4; db++) {
        u16x4 o;
        #pragma unroll
        for (int r = 0; r < 4; r++) o[r] = f2b(acco[db][r] * inv);
        *(u16x4*)(aop + db * 16) = o;
    }
}

extern "C" void kernel_launch(void* const* d_in, const int* in_sizes, int n_in,
                              void* d_out, int out_size, void* d_ws, size_t ws_size,
                              hipStream_t stream) {
    const float* x     = (const float*)d_in[0];
    const float* gamma = (const float*)d_in[1];
    const float* dist  = (const float*)d_in[2];
    const float* ln1w  = (const float*)d_in[3];
    const float* ln1b  = (const float*)d_in[4];
    const float* qkvw  = (const float*)d_in[5];
    const float* qkvb  = (const float*)d_in[6];
    const float* projw = (const float*)d_in[7];
    const float* projb = (const float*)d_in[8];
    const float* ln2w  = (const float*)d_in[9];
    const float* ln2b  = (const float*)d_in[10];
    const float* w1    = (const float*)d_in[11];
    const float* b1    = (const float*)d_in[12];
    const float* w2    = (const float*)d_in[13];
    const float* b2    = (const float*)d_in[14];
    float* out = (float*)d_out;
    char* ws = (char*)d_ws;
    u16* wqkvT  = (u16*)(ws + 0);
    u16* wprojT = (u16*)(ws + 6291456);
    u16* w1T    = (u16*)(ws + 8388608);
    u16* w2T    = (u16*)(ws + 16777216);
    u16* hb     = (u16*)(ws + 33554432);
    u16* qb     = (u16*)(ws + 41943040);
    u16* kb     = (u16*)(ws + 50331648);
    u16* vtb    = (u16*)(ws + 58720256);
    u16* aob    = (u16*)(ws + 67108864);
    u16* gb     = hb;    // mlp1 output [4096][4096] bf16 spans 33.5-67.1 MB
    u16* h2b    = aob;   // ln2 output reuses ao slot (dead after mlp1)
    // mlp2 split-K bf16 partials (8 MB each), in regions dead by mlp2:
    u16* mp0 = (u16*)(ws + 0);          // wqkvT+wprojT (dead after proj)
    u16* mp1 = (u16*)(ws + 8388608);    // w1T (dead after mlp1)
    u16* mp2 = (u16*)(ws + 25165824);   // unused region
    u16* mp3 = (u16*)(ws + 67108864);   // aob/h2b (dead after mlp1)

    dim3 blk(256);
    prep_fused<<<16384, blk, 0, stream>>>(qkvw, projw, w1, w2,
                                          wqkvT, wprojT, w1T, w2T,
                                          x, ln1w, ln1b, hb);
    gemm256_8ph<0><<<dim3(12, 16), dim3(512), 0, stream>>>(hb, wqkvT, qkvb, 1024, 1024,
                                                           nullptr, qb, kb, vtb);
    attn_fwd<<<dim3(16, 32), dim3(512), 0, stream>>>(qb, kb, vtb, dist, gamma, aob);
    gemm_bf16<1, 64><<<dim3(16, 32), blk, 0, stream>>>(aob, wprojT, projb, 4096, 1024, 1024,
                                                       x, out);
    ln_bf16<<<4096, blk, 0, stream>>>(out, ln2w, ln2b, h2b);
    gemm256_8ph<2><<<dim3(16, 16), dim3(512), 0, stream>>>(h2b, w1T, b1, 1024, 1024,
                                                           gb, nullptr, nullptr, nullptr);
    gemm256_8ph<3><<<dim3(4, 16, 4), dim3(512), 0, stream>>>(gb, w2T, nullptr, 4096, 1024,
                                                             mp0, mp1, mp2, mp3);
    combine4<<<4096, blk, 0, stream>>>(mp0, mp1, mp2, mp3, b2, out);
}